// Round 6
// baseline (77.245 us; speedup 1.0000x reference)
//
#include <hip/hip_runtime.h>
#include <hip/hip_bf16.h>
#include <stdint.h>

#define BB 64
#define TT 4096
#define NS 32
#define DD 64
#define CH 64      // chunks per subject
#define CL 64      // chunk length
#define WU 24      // warmup steps (mixing: contraction ~0.15/step -> ~1e-20)
#define LOG2PI 1.8378770664093453f
#define LN2F 0.6931471805599453f
#define FLT_MIN_NORM 1.175494350822288e-38f

typedef float f2 __attribute__((ext_vector_type(2)));

__device__ __forceinline__ f2 pk_fma(f2 a, f2 b, f2 c) {
  f2 d;
  asm("v_pk_fma_f32 %0, %1, %2, %3" : "=v"(d) : "v"(a), "v"(b), "v"(c));
  return d;
}

__device__ __forceinline__ uint32_t cvt_pk_bf16(float lo, float hi) {
  uint32_t d;
  asm("v_cvt_pk_bf16_f32 %0, %1, %2" : "=v"(d) : "v"(lo), "v"(hi));
  return d;
}

// sum over each 32-lane half; result valid in lanes 31 and 63
__device__ __forceinline__ float dpp_sum32(float v) {
  float r = v; int x;
  x = __builtin_amdgcn_update_dpp(0, __float_as_int(r), 0x111, 0xF, 0xF, true); r += __int_as_float(x);
  x = __builtin_amdgcn_update_dpp(0, __float_as_int(r), 0x112, 0xF, 0xF, true); r += __int_as_float(x);
  x = __builtin_amdgcn_update_dpp(0, __float_as_int(r), 0x114, 0xF, 0xF, true); r += __int_as_float(x);
  x = __builtin_amdgcn_update_dpp(0, __float_as_int(r), 0x118, 0xF, 0xF, true); r += __int_as_float(x);
  x = __builtin_amdgcn_update_dpp(0, __float_as_int(r), 0x142, 0xF, 0xF, true); r += __int_as_float(x);
  return r;
}

// max over all 64 lanes; result valid in lane 63
__device__ __forceinline__ float dpp_max64(float v) {
  float r = v; int x;
  x = __builtin_amdgcn_update_dpp(__float_as_int(r), __float_as_int(r), 0x111, 0xF, 0xF, false); r = fmaxf(r, __int_as_float(x));
  x = __builtin_amdgcn_update_dpp(__float_as_int(r), __float_as_int(r), 0x112, 0xF, 0xF, false); r = fmaxf(r, __int_as_float(x));
  x = __builtin_amdgcn_update_dpp(__float_as_int(r), __float_as_int(r), 0x114, 0xF, 0xF, false); r = fmaxf(r, __int_as_float(x));
  x = __builtin_amdgcn_update_dpp(__float_as_int(r), __float_as_int(r), 0x118, 0xF, 0xF, false); r = fmaxf(r, __int_as_float(x));
  x = __builtin_amdgcn_update_dpp(__float_as_int(r), __float_as_int(r), 0x142, 0xF, 0xF, false); r = fmaxf(r, __int_as_float(x));
  x = __builtin_amdgcn_update_dpp(__float_as_int(r), __float_as_int(r), 0x143, 0xF, 0xF, false); r = fmaxf(r, __int_as_float(x));
  return r;
}

// ---------------- K1: preprocess (wave-parallel; all loads coalesced)
__global__ __launch_bounds__(1024) void k_pre(
    const float* __restrict__ tm, const float* __restrict__ sp,
    const float* __restrict__ mus, const float* __restrict__ lv,
    float* __restrict__ Amat, float* __restrict__ pivec,
    float* __restrict__ UT, float* __restrict__ VT,
    float* __restrict__ bias)
{
  const int tid = threadIdx.x;       // 0..1023
  const int row = tid >> 5;          // 0..31
  const int col = tid & 31;          // 0..31

  // --- transition-matrix row softmax
  {
    float v = tm[row * 32 + col];
    float m = v;
    #pragma unroll
    for (int mask = 16; mask; mask >>= 1) m = fmaxf(m, __shfl_xor(m, mask));
    float e = __expf(v - m);
    float s = e;
    #pragma unroll
    for (int mask = 16; mask; mask >>= 1) s += __shfl_xor(s, mask);
    Amat[row * 32 + col] = e / s;
  }

  // --- state-prior softmax (lanes 0..31 of wave 0)
  if (tid < 32) {
    float v = sp[tid];
    float m = v;
    #pragma unroll
    for (int mask = 16; mask; mask >>= 1) m = fmaxf(m, __shfl_xor(m, mask));
    float e = __expf(v - m);
    float s = e;
    #pragma unroll
    for (int mask = 16; mask; mask >>= 1) s += __shfl_xor(s, mask);
    pivec[tid] = e / s;
  }

  // --- UT/VT transpose tables
  #pragma unroll
  for (int ii = 0; ii < 2; ++ii) {
    int i = tid + ii * 1024;          // 0..2047
    int n = i >> 6, d = i & 63;
    float iv = __expf(-lv[i]);
    UT[d * NS + n] = -0.5f * iv;
    VT[d * NS + n] = mus[i] * iv;
  }

  // --- bias[n] = -0.5*(sum mu^2*iv + sum lv + D*log2pi)
  {
    float s2 = 0.f, slv = 0.f;
    #pragma unroll
    for (int h = 0; h < 2; ++h) {
      int d = col + h * 32;
      float m_ = mus[row * 64 + d];
      float l_ = lv[row * 64 + d];
      s2 = fmaf(m_ * m_, __expf(-l_), s2);
      slv += l_;
    }
    #pragma unroll
    for (int mask = 16; mask; mask >>= 1) {
      s2  += __shfl_xor(s2, mask);
      slv += __shfl_xor(slv, mask);
    }
    if (col == 0) bias[row] = -0.5f * (s2 + slv + (float)DD * LOG2PI);
  }
}

// ---------------- K2: emission -> blin (bf16, shifted by per-chunk max Kc)
// R4-exact version: 256 threads / 128 t (2 chunks); 4 t-rows per thread;
// U/V in LDS; X from global via compiler-scheduled unroll-2 pipeline.
__global__ __launch_bounds__(256, 4) void k_emis(
    const float* __restrict__ Xg,
    const float* __restrict__ UT,
    const float* __restrict__ VT,
    const float* __restrict__ bias,
    uint32_t* __restrict__ blin32,
    float* __restrict__ Kc)
{
  __shared__ __align__(16) float Us[64][32];
  __shared__ __align__(16) float Vs[64][32];
  __shared__ float smax[4][2];                 // [wave][chunk-half]
  const int tid = threadIdx.x;
  const int blk = blockIdx.x;                  // 0..2047
  const int b  = blk >> 5;
  const int cc = blk & 31;                     // chunk-pair index
  const int t0 = cc << 7;                      // 128 t per block

  for (int i = tid; i < 64*32; i += 256) {
    Us[i >> 5][i & 31] = UT[i];
    Vs[i >> 5][i & 31] = VT[i];
  }
  __syncthreads();

  const int tq = tid >> 3;   // 0..31
  const int nq = tid & 7;    // 0..7
  const float* xbase = Xg + (size_t)(b*TT + t0) * DD;

  f2 acc[4][2];
  #pragma unroll
  for (int a = 0; a < 4; ++a) {
    acc[a][0].x = 0.f; acc[a][0].y = 0.f;
    acc[a][1].x = 0.f; acc[a][1].y = 0.f;
  }

  #pragma unroll 2
  for (int d0 = 0; d0 < 64; d0 += 4) {
    float4 xv[4];
    #pragma unroll
    for (int t4 = 0; t4 < 4; ++t4)
      xv[t4] = *(const float4*)&xbase[(size_t)(tq + (t4 << 5)) * DD + d0];
    #pragma unroll
    for (int dd = 0; dd < 4; ++dd) {
      const int d = d0 + dd;
      float4 u4 = *(const float4*)&Us[d][nq << 2];
      float4 v4 = *(const float4*)&Vs[d][nq << 2];
      f2 u01; u01.x = u4.x; u01.y = u4.y;
      f2 u23; u23.x = u4.z; u23.y = u4.w;
      f2 v01; v01.x = v4.x; v01.y = v4.y;
      f2 v23; v23.x = v4.z; v23.y = v4.w;
      #pragma unroll
      for (int t4 = 0; t4 < 4; ++t4) {
        float x = ((const float*)&xv[t4])[dd];
        f2 x2; x2.x = x; x2.y = x;
        f2 tmp0 = pk_fma(x2, u01, v01);
        f2 tmp1 = pk_fma(x2, u23, v23);
        acc[t4][0] = pk_fma(x2, tmp0, acc[t4][0]);
        acc[t4][1] = pk_fma(x2, tmp1, acc[t4][1]);
      }
    }
  }

  float b4[4];
  #pragma unroll
  for (int k = 0; k < 4; ++k) b4[k] = bias[(nq << 2) + k];

  float lb[4][4];
  float lmax0 = -1e30f, lmax1 = -1e30f;
  #pragma unroll
  for (int t4 = 0; t4 < 4; ++t4) {
    lb[t4][0] = acc[t4][0].x + b4[0];
    lb[t4][1] = acc[t4][0].y + b4[1];
    lb[t4][2] = acc[t4][1].x + b4[2];
    lb[t4][3] = acc[t4][1].y + b4[3];
    float m = fmaxf(fmaxf(lb[t4][0], lb[t4][1]), fmaxf(lb[t4][2], lb[t4][3]));
    if (t4 < 2) lmax0 = fmaxf(lmax0, m); else lmax1 = fmaxf(lmax1, m);
  }

  float wm0 = dpp_max64(lmax0);
  float wm1 = dpp_max64(lmax1);
  if ((tid & 63) == 63) { smax[tid >> 6][0] = wm0; smax[tid >> 6][1] = wm1; }
  __syncthreads();
  const float K0 = fmaxf(fmaxf(smax[0][0], smax[1][0]), fmaxf(smax[2][0], smax[3][0]));
  const float K1 = fmaxf(fmaxf(smax[0][1], smax[1][1]), fmaxf(smax[2][1], smax[3][1]));
  if (tid == 0) {
    Kc[(b << 6) + (cc << 1)]     = K0;
    Kc[(b << 6) + (cc << 1) + 1] = K1;
  }

  #pragma unroll
  for (int t4 = 0; t4 < 4; ++t4) {
    const int t = t0 + tq + (t4 << 5);
    const float KcV = (t4 < 2) ? K0 : K1;
    float e0 = __expf(lb[t4][0] - KcV);
    float e1 = __expf(lb[t4][1] - KcV);
    float e2 = __expf(lb[t4][2] - KcV);
    float e3 = __expf(lb[t4][3] - KcV);
    uint2 w;
    w.x = cvt_pk_bf16(e0, e1);
    w.y = cvt_pk_bf16(e2, e3);
    ((uint2*)blin32)[((size_t)(b*TT + t) << 3) + nq] = w;
  }
}

// ---------------- K3: chunked linear-space scan (2 chunks per wave)
__global__ __launch_bounds__(256, 2) void k_scan(
    const uint32_t* __restrict__ blin32,
    const float* __restrict__ Kc,
    const float* __restrict__ Amat,
    const float* __restrict__ pivec,
    float* __restrict__ out,
    float* __restrict__ Mc)
{
  __shared__ __align__(16) float vbuf[4][64];
  const int tid  = threadIdx.x;
  const int wave = tid >> 6;
  const int lane = tid & 63;
  const int half = lane >> 5;
  const int j    = lane & 31;
  const int wgid = blockIdx.x * 4 + wave;      // 0..2047
  const int g0   = wgid << 1;
  const int b    = g0 >> 6;
  const int c    = (g0 & 63) + half;           // this half's chunk
  const int cs   = c << 6;
  const bool isC0 = (c == 0);

  f2 col2[16];
  #pragma unroll
  for (int i = 0; i < 16; ++i) {
    col2[i].x = Amat[(2*i) * NS + j];
    col2[i].y = Amat[(2*i+1) * NS + j];
  }
  const float pij = pivec[j];
  const float KcH = Kc[(b << 6) + c];
  const int outbase = b * TT + cs;

  int tstart = cs - WU; if (tstart < 0) tstart = 0;  // only chunk 0 clamps
  int idx = (b * TT + tstart) * 16 + (j >> 1);
  const int idxMain = (b * TT + cs) * 16 + (j >> 1);
  const int shamt = (j & 1) ? 0 : 16;

  uint32_t bl[8];
  #pragma unroll
  for (int p = 0; p < 8; ++p) { bl[p] = blin32[idx]; idx += 16; }

  float v = 1.0f, S = 0.0f, sPrev = 1.0f;
  float* vb = &vbuf[wave][0];
  const float4* pv4 = (const float4*)(vb + (half << 5));

  auto STEP = [&](int q, int slot) {
    // consume s_{t-1}: rescale exponent + (in main phase) emit previous output
    float sP = fmaxf(sPrev, FLT_MIN_NORM);     // NaN-guard: stay normal
    int e = ((__float_as_int(sP) >> 23) & 0xFF) - 126;
    float rf = __int_as_float((127 - e) << 23);
    if (q >= WU) {
      float outv = __log2f(sP) * LN2F + S;
      if (q == WU) {
        if ((lane & 31) == 0) Mc[(b << 6) + c] = outv;
      } else {
        if ((lane & 31) == 0) out[outbase + (q - WU) - 1] = outv;
      }
      S += KcH + (float)e * LN2F;
    } else {
      S += (float)e * LN2F;
    }
    // matvec via LDS broadcast
    vb[lane] = v;
    f2 a0; a0.x = 0.f; a0.y = 0.f;
    f2 a1; a1.x = 0.f; a1.y = 0.f;
    #pragma unroll
    for (int k = 0; k < 8; ++k) {
      float4 p = pv4[k];
      f2 plo; plo.x = p.x; plo.y = p.y;
      f2 phi; phi.x = p.z; phi.y = p.w;
      a0 = pk_fma(plo, col2[2*k],   a0);
      a1 = pk_fma(phi, col2[2*k+1], a1);
    }
    float dot = (a0.x + a0.y) + (a1.x + a1.y);
    if (q == WU) dot = isC0 ? v : dot;          // chunk 0: alpha0 = pi (no transition)
    if (q == WU - 8) idx = idxMain;             // prefetch stream jumps to main phase
    uint32_t raw = bl[slot];
    bl[slot] = blin32[idx]; idx += 16;          // prefetch step q+8
    float blf = __int_as_float((raw << shamt) & 0xFFFF0000u);
    v = dot * blf * rf;
    if (q == WU - 1) { if (isC0) { v = pij; S = 0.0f; } }  // reset chunk 0 before main
    float r = dpp_sum32(v);
    sPrev = __int_as_float(__builtin_amdgcn_ds_swizzle(__float_as_int(r), 0x3E0));
  };

  #pragma unroll 1
  for (int m = 0; m < (WU + CL) / 8; ++m) {
    const int q0 = m << 3;
    STEP(q0 + 0, 0); STEP(q0 + 1, 1); STEP(q0 + 2, 2); STEP(q0 + 3, 3);
    STEP(q0 + 4, 4); STEP(q0 + 5, 5); STEP(q0 + 6, 6); STEP(q0 + 7, 7);
  }
  {
    float sP = fmaxf(sPrev, FLT_MIN_NORM);
    float outv = __log2f(sP) * LN2F + S;
    if ((lane & 31) == 0) out[outbase + CL - 1] = outv;
  }
}

// ---------------- K4a: per-subject prefix of chunk offsets
__global__ void k_stitch(const float* __restrict__ out, const float* __restrict__ Mcc,
                         float* __restrict__ Delta)
{
  const int b = blockIdx.x;
  const int c = threadIdx.x;     // 64 threads
  float term = 0.0f;
  if (c > 0) term = out[b * TT + (c << 6) - 1] - Mcc[(b << 6) + c];
  for (int off = 1; off < 64; off <<= 1) {
    float up = __shfl_up(term, off);
    if (c >= off) term += up;
  }
  Delta[(b << 6) + c] = term;
}

// ---------------- K4b: add offsets
__global__ void k_add(float* __restrict__ out, const float* __restrict__ Delta)
{
  const int i = blockIdx.x * 256 + threadIdx.x;   // i < B*T
  const int b = i >> 12;
  const int t = i & 4095;
  out[i] += Delta[(b << 6) + (t >> 6)];
}

extern "C" void kernel_launch(void* const* d_in, const int* in_sizes, int n_in,
                              void* d_out, int out_size, void* d_ws, size_t ws_size,
                              hipStream_t stream) {
  const float* X   = (const float*)d_in[0];
  const float* tm  = (const float*)d_in[1];
  const float* sp  = (const float*)d_in[2];
  const float* mus = (const float*)d_in[3];
  const float* lv  = (const float*)d_in[4];
  float* out = (float*)d_out;

  char* ws = (char*)d_ws;
  size_t off = 0;
  uint32_t* blin32 = (uint32_t*)(ws + off); off += (size_t)BB * TT * NS * 2 + 4096;
  float* Kcv   = (float*)(ws + off); off += (size_t)BB * CH * 4;
  float* Mcc   = (float*)(ws + off); off += (size_t)BB * CH * 4;
  float* Delta = (float*)(ws + off); off += (size_t)BB * CH * 4;
  float* Amat  = (float*)(ws + off); off += (size_t)NS * NS * 4;
  float* pivec = (float*)(ws + off); off += 256;
  float* UT    = (float*)(ws + off); off += (size_t)NS * DD * 4;
  float* VT    = (float*)(ws + off); off += (size_t)NS * DD * 4;
  float* bias  = (float*)(ws + off); off += 256;

  k_pre<<<dim3(1), dim3(1024), 0, stream>>>(tm, sp, mus, lv, Amat, pivec, UT, VT, bias);
  k_emis<<<dim3(BB * CH / 2), dim3(256), 0, stream>>>(X, UT, VT, bias, blin32, Kcv);
  k_scan<<<dim3(512), dim3(256), 0, stream>>>(blin32, Kcv, Amat, pivec, out, Mcc);
  k_stitch<<<dim3(BB), dim3(64), 0, stream>>>(out, Mcc, Delta);
  k_add<<<dim3((BB * TT) / 256), dim3(256), 0, stream>>>(out, Delta);
}

// Round 7
// 73.064 us; speedup vs baseline: 1.0572x; 1.0572x over previous
//
#include <hip/hip_runtime.h>
#include <hip/hip_bf16.h>
#include <stdint.h>

#define BB 64
#define TT 4096
#define NS 32
#define DD 64
#define CH 128     // chunks per subject
#define CL 32      // chunk length
#define WU 16      // warmup steps (Birkhoff tau~0.15/step -> 7e-14 after 16)
#define LOG2PI 1.8378770664093453f
#define LN2F 0.6931471805599453f
#define FLT_MIN_NORM 1.175494350822288e-38f

typedef float f2 __attribute__((ext_vector_type(2)));

__device__ __forceinline__ f2 pk_fma(f2 a, f2 b, f2 c) {
  f2 d;
  asm("v_pk_fma_f32 %0, %1, %2, %3" : "=v"(d) : "v"(a), "v"(b), "v"(c));
  return d;
}

__device__ __forceinline__ uint32_t cvt_pk_bf16(float lo, float hi) {
  uint32_t d;
  asm("v_cvt_pk_bf16_f32 %0, %1, %2" : "=v"(d) : "v"(lo), "v"(hi));
  return d;
}

// sum over each 32-lane half; result valid in lanes 31 and 63
__device__ __forceinline__ float dpp_sum32(float v) {
  float r = v; int x;
  x = __builtin_amdgcn_update_dpp(0, __float_as_int(r), 0x111, 0xF, 0xF, true); r += __int_as_float(x);
  x = __builtin_amdgcn_update_dpp(0, __float_as_int(r), 0x112, 0xF, 0xF, true); r += __int_as_float(x);
  x = __builtin_amdgcn_update_dpp(0, __float_as_int(r), 0x114, 0xF, 0xF, true); r += __int_as_float(x);
  x = __builtin_amdgcn_update_dpp(0, __float_as_int(r), 0x118, 0xF, 0xF, true); r += __int_as_float(x);
  x = __builtin_amdgcn_update_dpp(0, __float_as_int(r), 0x142, 0xF, 0xF, true); r += __int_as_float(x);
  return r;
}

// max over all 64 lanes; result valid in lane 63
__device__ __forceinline__ float dpp_max64(float v) {
  float r = v; int x;
  x = __builtin_amdgcn_update_dpp(__float_as_int(r), __float_as_int(r), 0x111, 0xF, 0xF, false); r = fmaxf(r, __int_as_float(x));
  x = __builtin_amdgcn_update_dpp(__float_as_int(r), __float_as_int(r), 0x112, 0xF, 0xF, false); r = fmaxf(r, __int_as_float(x));
  x = __builtin_amdgcn_update_dpp(__float_as_int(r), __float_as_int(r), 0x114, 0xF, 0xF, false); r = fmaxf(r, __int_as_float(x));
  x = __builtin_amdgcn_update_dpp(__float_as_int(r), __float_as_int(r), 0x118, 0xF, 0xF, false); r = fmaxf(r, __int_as_float(x));
  x = __builtin_amdgcn_update_dpp(__float_as_int(r), __float_as_int(r), 0x142, 0xF, 0xF, false); r = fmaxf(r, __int_as_float(x));
  x = __builtin_amdgcn_update_dpp(__float_as_int(r), __float_as_int(r), 0x143, 0xF, 0xF, false); r = fmaxf(r, __int_as_float(x));
  return r;
}

// ---------------- K1: preprocess (wave-parallel; all loads coalesced)
__global__ __launch_bounds__(1024) void k_pre(
    const float* __restrict__ tm, const float* __restrict__ sp,
    const float* __restrict__ mus, const float* __restrict__ lv,
    float* __restrict__ Amat, float* __restrict__ pivec,
    float* __restrict__ UT, float* __restrict__ VT,
    float* __restrict__ bias)
{
  const int tid = threadIdx.x;       // 0..1023
  const int row = tid >> 5;          // 0..31
  const int col = tid & 31;          // 0..31

  // --- transition-matrix row softmax
  {
    float v = tm[row * 32 + col];
    float m = v;
    #pragma unroll
    for (int mask = 16; mask; mask >>= 1) m = fmaxf(m, __shfl_xor(m, mask));
    float e = __expf(v - m);
    float s = e;
    #pragma unroll
    for (int mask = 16; mask; mask >>= 1) s += __shfl_xor(s, mask);
    Amat[row * 32 + col] = e / s;
  }

  // --- state-prior softmax (lanes 0..31 of wave 0)
  if (tid < 32) {
    float v = sp[tid];
    float m = v;
    #pragma unroll
    for (int mask = 16; mask; mask >>= 1) m = fmaxf(m, __shfl_xor(m, mask));
    float e = __expf(v - m);
    float s = e;
    #pragma unroll
    for (int mask = 16; mask; mask >>= 1) s += __shfl_xor(s, mask);
    pivec[tid] = e / s;
  }

  // --- UT/VT transpose tables
  #pragma unroll
  for (int ii = 0; ii < 2; ++ii) {
    int i = tid + ii * 1024;          // 0..2047
    int n = i >> 6, d = i & 63;
    float iv = __expf(-lv[i]);
    UT[d * NS + n] = -0.5f * iv;
    VT[d * NS + n] = mus[i] * iv;
  }

  // --- bias[n] = -0.5*(sum mu^2*iv + sum lv + D*log2pi)
  {
    float s2 = 0.f, slv = 0.f;
    #pragma unroll
    for (int h = 0; h < 2; ++h) {
      int d = col + h * 32;
      float m_ = mus[row * 64 + d];
      float l_ = lv[row * 64 + d];
      s2 = fmaf(m_ * m_, __expf(-l_), s2);
      slv += l_;
    }
    #pragma unroll
    for (int mask = 16; mask; mask >>= 1) {
      s2  += __shfl_xor(s2, mask);
      slv += __shfl_xor(slv, mask);
    }
    if (col == 0) bias[row] = -0.5f * (s2 + slv + (float)DD * LOG2PI);
  }
}

// ---------------- K2: emission -> blin (bf16, shifted by per-chunk max Kc)
// 256 threads / 128 t (4 chunks of 32); 4 t-rows per thread; U/V in LDS;
// X from global via compiler-scheduled unroll-2 pipeline. Each t4 slab is
// exactly one 32-t chunk -> 4 per-chunk maxes per block.
__global__ __launch_bounds__(256, 4) void k_emis(
    const float* __restrict__ Xg,
    const float* __restrict__ UT,
    const float* __restrict__ VT,
    const float* __restrict__ bias,
    uint32_t* __restrict__ blin32,
    float* __restrict__ Kc)
{
  __shared__ __align__(16) float Us[64][32];
  __shared__ __align__(16) float Vs[64][32];
  __shared__ float smax[4][4];                 // [wave][t4-chunk]
  const int tid = threadIdx.x;
  const int blk = blockIdx.x;                  // 0..2047
  const int b  = blk >> 5;
  const int cc = blk & 31;                     // 128-t slab index
  const int t0 = cc << 7;                      // 128 t per block

  for (int i = tid; i < 64*32; i += 256) {
    Us[i >> 5][i & 31] = UT[i];
    Vs[i >> 5][i & 31] = VT[i];
  }
  __syncthreads();

  const int tq = tid >> 3;   // 0..31
  const int nq = tid & 7;    // 0..7
  const float* xbase = Xg + (size_t)(b*TT + t0) * DD;

  f2 acc[4][2];
  #pragma unroll
  for (int a = 0; a < 4; ++a) {
    acc[a][0].x = 0.f; acc[a][0].y = 0.f;
    acc[a][1].x = 0.f; acc[a][1].y = 0.f;
  }

  #pragma unroll 2
  for (int d0 = 0; d0 < 64; d0 += 4) {
    float4 xv[4];
    #pragma unroll
    for (int t4 = 0; t4 < 4; ++t4)
      xv[t4] = *(const float4*)&xbase[(size_t)(tq + (t4 << 5)) * DD + d0];
    #pragma unroll
    for (int dd = 0; dd < 4; ++dd) {
      const int d = d0 + dd;
      float4 u4 = *(const float4*)&Us[d][nq << 2];
      float4 v4 = *(const float4*)&Vs[d][nq << 2];
      f2 u01; u01.x = u4.x; u01.y = u4.y;
      f2 u23; u23.x = u4.z; u23.y = u4.w;
      f2 v01; v01.x = v4.x; v01.y = v4.y;
      f2 v23; v23.x = v4.z; v23.y = v4.w;
      #pragma unroll
      for (int t4 = 0; t4 < 4; ++t4) {
        float x = ((const float*)&xv[t4])[dd];
        f2 x2; x2.x = x; x2.y = x;
        f2 tmp0 = pk_fma(x2, u01, v01);
        f2 tmp1 = pk_fma(x2, u23, v23);
        acc[t4][0] = pk_fma(x2, tmp0, acc[t4][0]);
        acc[t4][1] = pk_fma(x2, tmp1, acc[t4][1]);
      }
    }
  }

  float b4[4];
  #pragma unroll
  for (int k = 0; k < 4; ++k) b4[k] = bias[(nq << 2) + k];

  float lb[4][4];
  float wm[4];
  #pragma unroll
  for (int t4 = 0; t4 < 4; ++t4) {
    lb[t4][0] = acc[t4][0].x + b4[0];
    lb[t4][1] = acc[t4][0].y + b4[1];
    lb[t4][2] = acc[t4][1].x + b4[2];
    lb[t4][3] = acc[t4][1].y + b4[3];
    float m = fmaxf(fmaxf(lb[t4][0], lb[t4][1]), fmaxf(lb[t4][2], lb[t4][3]));
    wm[t4] = dpp_max64(m);
  }
  if ((tid & 63) == 63) {
    #pragma unroll
    for (int t4 = 0; t4 < 4; ++t4) smax[tid >> 6][t4] = wm[t4];
  }
  __syncthreads();
  float K4[4];
  #pragma unroll
  for (int t4 = 0; t4 < 4; ++t4)
    K4[t4] = fmaxf(fmaxf(smax[0][t4], smax[1][t4]), fmaxf(smax[2][t4], smax[3][t4]));
  if (tid < 4) Kc[(b << 7) + (cc << 2) + tid] = K4[tid];

  #pragma unroll
  for (int t4 = 0; t4 < 4; ++t4) {
    const int t = t0 + tq + (t4 << 5);
    const float KcV = K4[t4];
    float e0 = __expf(lb[t4][0] - KcV);
    float e1 = __expf(lb[t4][1] - KcV);
    float e2 = __expf(lb[t4][2] - KcV);
    float e3 = __expf(lb[t4][3] - KcV);
    uint2 w;
    w.x = cvt_pk_bf16(e0, e1);
    w.y = cvt_pk_bf16(e2, e3);
    ((uint2*)blin32)[((size_t)(b*TT + t) << 3) + nq] = w;
  }
}

// ---------------- K3: chunked linear-space scan (2 chunks per wave)
// CL=32, WU=16: 48 serial steps; 4096 waves -> 4 waves/SIMD latency hiding.
__global__ __launch_bounds__(256, 2) void k_scan(
    const uint32_t* __restrict__ blin32,
    const float* __restrict__ Kc,
    const float* __restrict__ Amat,
    const float* __restrict__ pivec,
    float* __restrict__ out,
    float* __restrict__ Mc)
{
  __shared__ __align__(16) float vbuf[4][64];
  const int tid  = threadIdx.x;
  const int wave = tid >> 6;
  const int lane = tid & 63;
  const int half = lane >> 5;
  const int j    = lane & 31;
  const int wgid = blockIdx.x * 4 + wave;      // 0..4095
  const int g0   = wgid << 1;
  const int b    = g0 >> 7;
  const int c    = (g0 & 127) + half;          // this half's chunk (0..127)
  const int cs   = c << 5;
  const bool isC0 = (c == 0);

  f2 col2[16];
  #pragma unroll
  for (int i = 0; i < 16; ++i) {
    col2[i].x = Amat[(2*i) * NS + j];
    col2[i].y = Amat[(2*i+1) * NS + j];
  }
  const float pij = pivec[j];
  const float KcH = Kc[(b << 7) + c];
  const int outbase = b * TT + cs;

  int tstart = cs - WU; if (tstart < 0) tstart = 0;  // only chunk 0 clamps
  int idx = (b * TT + tstart) * 16 + (j >> 1);
  const int idxMain = (b * TT + cs) * 16 + (j >> 1);
  const int shamt = (j & 1) ? 0 : 16;

  uint32_t bl[8];
  #pragma unroll
  for (int p = 0; p < 8; ++p) { bl[p] = blin32[idx]; idx += 16; }

  float v = 1.0f, S = 0.0f, sPrev = 1.0f;
  float* vb = &vbuf[wave][0];
  const float4* pv4 = (const float4*)(vb + (half << 5));

  auto STEP = [&](int q, int slot) {
    // consume s_{t-1}: rescale exponent + (in main phase) emit previous output
    float sP = fmaxf(sPrev, FLT_MIN_NORM);     // NaN-guard: stay normal
    int e = ((__float_as_int(sP) >> 23) & 0xFF) - 126;
    float rf = __int_as_float((127 - e) << 23);
    if (q >= WU) {
      float outv = __log2f(sP) * LN2F + S;
      if (q == WU) {
        if ((lane & 31) == 0) Mc[(b << 7) + c] = outv;
      } else {
        if ((lane & 31) == 0) out[outbase + (q - WU) - 1] = outv;
      }
      S += KcH + (float)e * LN2F;
    } else {
      S += (float)e * LN2F;
    }
    // matvec via LDS broadcast
    vb[lane] = v;
    f2 a0; a0.x = 0.f; a0.y = 0.f;
    f2 a1; a1.x = 0.f; a1.y = 0.f;
    #pragma unroll
    for (int k = 0; k < 8; ++k) {
      float4 p = pv4[k];
      f2 plo; plo.x = p.x; plo.y = p.y;
      f2 phi; phi.x = p.z; phi.y = p.w;
      a0 = pk_fma(plo, col2[2*k],   a0);
      a1 = pk_fma(phi, col2[2*k+1], a1);
    }
    float dot = (a0.x + a0.y) + (a1.x + a1.y);
    if (q == WU) dot = isC0 ? v : dot;          // chunk 0: alpha0 = pi (no transition)
    if (q == WU - 8) idx = idxMain;             // prefetch stream jumps to main phase
    uint32_t raw = bl[slot];
    bl[slot] = blin32[idx]; idx += 16;          // prefetch step q+8
    float blf = __int_as_float((raw << shamt) & 0xFFFF0000u);
    v = dot * blf * rf;
    if (q == WU - 1) { if (isC0) { v = pij; S = 0.0f; } }  // reset chunk 0 before main
    float r = dpp_sum32(v);
    sPrev = __int_as_float(__builtin_amdgcn_ds_swizzle(__float_as_int(r), 0x3E0));
  };

  #pragma unroll 1
  for (int m = 0; m < (WU + CL) / 8; ++m) {
    const int q0 = m << 3;
    STEP(q0 + 0, 0); STEP(q0 + 1, 1); STEP(q0 + 2, 2); STEP(q0 + 3, 3);
    STEP(q0 + 4, 4); STEP(q0 + 5, 5); STEP(q0 + 6, 6); STEP(q0 + 7, 7);
  }
  {
    float sP = fmaxf(sPrev, FLT_MIN_NORM);
    float outv = __log2f(sP) * LN2F + S;
    if ((lane & 31) == 0) out[outbase + CL - 1] = outv;
  }
}

// ---------------- K4a: per-subject prefix of chunk offsets (128 chunks)
__global__ void k_stitch(const float* __restrict__ out, const float* __restrict__ Mcc,
                         float* __restrict__ Delta)
{
  __shared__ float w0sum;
  const int b = blockIdx.x;
  const int c = threadIdx.x;     // 0..127 (2 waves)
  float term = 0.0f;
  if (c > 0) term = out[b * TT + (c << 5) - 1] - Mcc[(b << 7) + c];
  for (int off = 1; off < 64; off <<= 1) {
    float up = __shfl_up(term, off);
    if ((c & 63) >= off) term += up;
  }
  if (c == 63) w0sum = term;
  __syncthreads();
  if (c >= 64) term += w0sum;
  Delta[(b << 7) + c] = term;
}

// ---------------- K4b: add offsets
__global__ void k_add(float* __restrict__ out, const float* __restrict__ Delta)
{
  const int i = blockIdx.x * 256 + threadIdx.x;   // i < B*T
  const int b = i >> 12;
  const int t = i & 4095;
  out[i] += Delta[(b << 7) + (t >> 5)];
}

extern "C" void kernel_launch(void* const* d_in, const int* in_sizes, int n_in,
                              void* d_out, int out_size, void* d_ws, size_t ws_size,
                              hipStream_t stream) {
  const float* X   = (const float*)d_in[0];
  const float* tm  = (const float*)d_in[1];
  const float* sp  = (const float*)d_in[2];
  const float* mus = (const float*)d_in[3];
  const float* lv  = (const float*)d_in[4];
  float* out = (float*)d_out;

  char* ws = (char*)d_ws;
  size_t off = 0;
  uint32_t* blin32 = (uint32_t*)(ws + off); off += (size_t)BB * TT * NS * 2 + 4096;
  float* Kcv   = (float*)(ws + off); off += (size_t)BB * CH * 4;
  float* Mcc   = (float*)(ws + off); off += (size_t)BB * CH * 4;
  float* Delta = (float*)(ws + off); off += (size_t)BB * CH * 4;
  float* Amat  = (float*)(ws + off); off += (size_t)NS * NS * 4;
  float* pivec = (float*)(ws + off); off += 256;
  float* UT    = (float*)(ws + off); off += (size_t)NS * DD * 4;
  float* VT    = (float*)(ws + off); off += (size_t)NS * DD * 4;
  float* bias  = (float*)(ws + off); off += 256;

  k_pre<<<dim3(1), dim3(1024), 0, stream>>>(tm, sp, mus, lv, Amat, pivec, UT, VT, bias);
  k_emis<<<dim3(2048), dim3(256), 0, stream>>>(X, UT, VT, bias, blin32, Kcv);
  k_scan<<<dim3(1024), dim3(256), 0, stream>>>(blin32, Kcv, Amat, pivec, out, Mcc);
  k_stitch<<<dim3(BB), dim3(128), 0, stream>>>(out, Mcc, Delta);
  k_add<<<dim3((BB * TT) / 256), dim3(256), 0, stream>>>(out, Delta);
}

// Round 9
// 54.199 us; speedup vs baseline: 1.4252x; 1.3481x over previous
//
#include <hip/hip_runtime.h>
#include <hip/hip_bf16.h>
#include <stdint.h>

#define BB 64
#define TT 4096
#define NS 32
#define DD 64
#define CH 128     // chunks per subject
#define CL 32      // chunk length
#define WU 16      // warmup steps (Birkhoff tau~0.15/step -> 7e-14 after 16)
#define LOG2PI 1.8378770664093453f
#define LN2F 0.6931471805599453f
#define FLT_MIN_NORM 1.175494350822288e-38f

typedef float f2 __attribute__((ext_vector_type(2)));
typedef float f32x16 __attribute__((ext_vector_type(16)));
typedef __bf16 bf16x8 __attribute__((ext_vector_type(8)));

__device__ __forceinline__ f2 pk_fma(f2 a, f2 b, f2 c) {
  f2 d;
  asm("v_pk_fma_f32 %0, %1, %2, %3" : "=v"(d) : "v"(a), "v"(b), "v"(c));
  return d;
}

__device__ __forceinline__ uint32_t cvt_pk_bf16(float lo, float hi) {
  uint32_t d;
  asm("v_cvt_pk_bf16_f32 %0, %1, %2" : "=v"(d) : "v"(lo), "v"(hi));
  return d;
}

// sum over each 32-lane half; result valid in lanes 31 and 63
__device__ __forceinline__ float dpp_sum32(float v) {
  float r = v; int x;
  x = __builtin_amdgcn_update_dpp(0, __float_as_int(r), 0x111, 0xF, 0xF, true); r += __int_as_float(x);
  x = __builtin_amdgcn_update_dpp(0, __float_as_int(r), 0x112, 0xF, 0xF, true); r += __int_as_float(x);
  x = __builtin_amdgcn_update_dpp(0, __float_as_int(r), 0x114, 0xF, 0xF, true); r += __int_as_float(x);
  x = __builtin_amdgcn_update_dpp(0, __float_as_int(r), 0x118, 0xF, 0xF, true); r += __int_as_float(x);
  x = __builtin_amdgcn_update_dpp(0, __float_as_int(r), 0x142, 0xF, 0xF, true); r += __int_as_float(x);
  return r;
}

// max over all 64 lanes; result valid in lane 63
__device__ __forceinline__ float dpp_max64(float v) {
  float r = v; int x;
  x = __builtin_amdgcn_update_dpp(__float_as_int(r), __float_as_int(r), 0x111, 0xF, 0xF, false); r = fmaxf(r, __int_as_float(x));
  x = __builtin_amdgcn_update_dpp(__float_as_int(r), __float_as_int(r), 0x112, 0xF, 0xF, false); r = fmaxf(r, __int_as_float(x));
  x = __builtin_amdgcn_update_dpp(__float_as_int(r), __float_as_int(r), 0x114, 0xF, 0xF, false); r = fmaxf(r, __int_as_float(x));
  x = __builtin_amdgcn_update_dpp(__float_as_int(r), __float_as_int(r), 0x118, 0xF, 0xF, false); r = fmaxf(r, __int_as_float(x));
  x = __builtin_amdgcn_update_dpp(__float_as_int(r), __float_as_int(r), 0x142, 0xF, 0xF, false); r = fmaxf(r, __int_as_float(x));
  x = __builtin_amdgcn_update_dpp(__float_as_int(r), __float_as_int(r), 0x143, 0xF, 0xF, false); r = fmaxf(r, __int_as_float(x));
  return r;
}

// ---------------- K1: preprocess (wave-parallel; all loads coalesced)
// Outputs: Amat, pivec (softmaxed), bias, and Wp: the MFMA B-operand table.
// Wp layout: u32[((n*2 + h)*8 + kk)*4 + j] = pack_bf16(-0.5*iv, mu*iv) for
// d = 8*kk + 4*h + j  (slot bijection shared with A-fragment construction).
__global__ __launch_bounds__(1024) void k_pre(
    const float* __restrict__ tm, const float* __restrict__ sp,
    const float* __restrict__ mus, const float* __restrict__ lv,
    float* __restrict__ Amat, float* __restrict__ pivec,
    uint32_t* __restrict__ Wp, float* __restrict__ bias)
{
  const int tid = threadIdx.x;       // 0..1023
  const int row = tid >> 5;          // 0..31  (state n)
  const int col = tid & 31;          // 0..31

  // --- transition-matrix row softmax
  {
    float v = tm[row * 32 + col];
    float m = v;
    #pragma unroll
    for (int mask = 16; mask; mask >>= 1) m = fmaxf(m, __shfl_xor(m, mask));
    float e = __expf(v - m);
    float s = e;
    #pragma unroll
    for (int mask = 16; mask; mask >>= 1) s += __shfl_xor(s, mask);
    Amat[row * 32 + col] = e / s;
  }

  // --- state-prior softmax (lanes 0..31 of wave 0)
  if (tid < 32) {
    float v = sp[tid];
    float m = v;
    #pragma unroll
    for (int mask = 16; mask; mask >>= 1) m = fmaxf(m, __shfl_xor(m, mask));
    float e = __expf(v - m);
    float s = e;
    #pragma unroll
    for (int mask = 16; mask; mask >>= 1) s += __shfl_xor(s, mask);
    pivec[tid] = e / s;
  }

  // --- Wp fragment table (bf16 pairs)
  #pragma unroll
  for (int hh = 0; hh < 2; ++hh) {
    int d = col + (hh << 5);             // 0..63
    float iv = __expf(-lv[row * 64 + d]);
    uint32_t w = cvt_pk_bf16(-0.5f * iv, mus[row * 64 + d] * iv);
    int kk = d >> 3, h2 = (d >> 2) & 1, j = d & 3;
    Wp[(((row << 1) + h2) * 8 + kk) * 4 + j] = w;
  }

  // --- bias[n] = -0.5*(sum mu^2*iv + sum lv + D*log2pi)
  {
    float s2 = 0.f, slv = 0.f;
    #pragma unroll
    for (int h = 0; h < 2; ++h) {
      int d = col + h * 32;
      float m_ = mus[row * 64 + d];
      float l_ = lv[row * 64 + d];
      s2 = fmaf(m_ * m_, __expf(-l_), s2);
      slv += l_;
    }
    #pragma unroll
    for (int mask = 16; mask; mask >>= 1) {
      s2  += __shfl_xor(s2, mask);
      slv += __shfl_xor(slv, mask);
    }
    if (col == 0) bias[row] = -0.5f * (s2 + slv + (float)DD * LOG2PI);
  }
}

// ---------------- K2: emission via MFMA -> blin (bf16, shifted by per-chunk max)
// One wave = one 32-t chunk x 32 states, K=128 ([x^2; x] over d). No LDS.
// A-frag: lane (t=l&31, h=l>>5), frag kk: float4 X[t][8kk+4h .. +3] ->
//   4x cvt_pk_bf16(x*x, x). B-frag: Wp table, same slot bijection -> the HW
//   k-ordering cancels. C layout (HW-verified): col=lane&31,
//   row=(reg&3)+8*(reg>>2)+4*(lane>>5).
__global__ __launch_bounds__(256, 4) void k_emis(
    const float* __restrict__ Xg,
    const uint32_t* __restrict__ Wp,
    const float* __restrict__ bias,
    uint32_t* __restrict__ blin32,
    float* __restrict__ Kc)
{
  const int tid = threadIdx.x;
  const int l   = tid & 63;
  const int w   = tid >> 6;            // wave 0..3
  const int bid = blockIdx.x;          // 0..2047
  const int b   = bid >> 5;
  const int cc  = bid & 31;
  const int chunk = (cc << 2) + w;     // 0..127
  const int t0w = chunk << 5;          // chunk start (t within subject)
  const int n   = l & 31;              // A-row / B-col / C-col
  const int h   = l >> 5;              // k-half

  // B fragments (8 x uint4 = 8 x 8 bf16), all-wave shared table (L2-hot)
  uint4 wf[8];
  const uint4* wp4 = (const uint4*)(Wp + ((n << 1) + h) * 32);
  #pragma unroll
  for (int kk = 0; kk < 8; ++kk) wf[kk] = wp4[kk];

  // X row pointer for this lane: row t0w+n, d-offset 4h
  const float* xr = Xg + (size_t)(b * TT + t0w + n) * DD + (h << 2);

  f32x16 acc;
  #pragma unroll
  for (int r = 0; r < 16; ++r) acc[r] = 0.0f;

  #pragma unroll
  for (int kk = 0; kk < 8; ++kk) {
    float4 x4 = *(const float4*)(xr + (kk << 3));
    uint4 au;
    au.x = cvt_pk_bf16(x4.x * x4.x, x4.x);
    au.y = cvt_pk_bf16(x4.y * x4.y, x4.y);
    au.z = cvt_pk_bf16(x4.z * x4.z, x4.z);
    au.w = cvt_pk_bf16(x4.w * x4.w, x4.w);
    bf16x8 af = __builtin_bit_cast(bf16x8, au);
    bf16x8 bf = __builtin_bit_cast(bf16x8, wf[kk]);
    acc = __builtin_amdgcn_mfma_f32_32x32x16_bf16(af, bf, acc, 0, 0, 0);
  }

  // epilogue: bias, wave-local chunk max, exp, pack, store
  const float bn = bias[n];
  float lb[16];
  float m = -1e30f;
  #pragma unroll
  for (int r = 0; r < 16; ++r) {
    lb[r] = acc[r] + bn;
    m = fmaxf(m, lb[r]);
  }
  m = dpp_max64(m);
  const float Km = __int_as_float(__builtin_amdgcn_readlane(__float_as_int(m), 63));
  if (l == 0) Kc[(b << 7) + chunk] = Km;

  const int tb = b * TT + t0w;
  #pragma unroll
  for (int r = 0; r < 16; ++r) {
    float e = __expf(lb[r] - Km);
    int nb = __builtin_amdgcn_update_dpp(0, __float_as_int(e), 0xB1, 0xF, 0xF, true); // lane^1
    uint32_t pk = cvt_pk_bf16(e, __int_as_float(nb));   // lo = even n, hi = odd n
    const int trow = (r & 3) + ((r >> 2) << 3) + (h << 2);
    if ((l & 1) == 0)
      blin32[(size_t)(tb + trow) * 16 + (n >> 1)] = pk;
  }
}

// ---------------- K3: chunked linear-space scan (2 chunks per wave)
// CL=32, WU=16: 48 serial steps; 4096 waves -> 4 waves/SIMD latency hiding.
__global__ __launch_bounds__(256, 2) void k_scan(
    const uint32_t* __restrict__ blin32,
    const float* __restrict__ Kc,
    const float* __restrict__ Amat,
    const float* __restrict__ pivec,
    float* __restrict__ out,
    float* __restrict__ Mc)
{
  __shared__ __align__(16) float vbuf[4][64];
  const int tid  = threadIdx.x;
  const int wave = tid >> 6;
  const int lane = tid & 63;
  const int half = lane >> 5;
  const int j    = lane & 31;
  const int wgid = blockIdx.x * 4 + wave;      // 0..4095
  const int g0   = wgid << 1;
  const int b    = g0 >> 7;
  const int c    = (g0 & 127) + half;          // this half's chunk (0..127)
  const int cs   = c << 5;
  const bool isC0 = (c == 0);

  f2 col2[16];
  #pragma unroll
  for (int i = 0; i < 16; ++i) {
    col2[i].x = Amat[(2*i) * NS + j];
    col2[i].y = Amat[(2*i+1) * NS + j];
  }
  const float pij = pivec[j];
  const float KcH = Kc[(b << 7) + c];
  const int outbase = b * TT + cs;

  int tstart = cs - WU; if (tstart < 0) tstart = 0;  // only chunk 0 clamps
  int idx = (b * TT + tstart) * 16 + (j >> 1);
  const int idxMain = (b * TT + cs) * 16 + (j >> 1);
  const int shamt = (j & 1) ? 0 : 16;

  uint32_t bl[8];
  #pragma unroll
  for (int p = 0; p < 8; ++p) { bl[p] = blin32[idx]; idx += 16; }

  float v = 1.0f, S = 0.0f, sPrev = 1.0f;
  float* vb = &vbuf[wave][0];
  const float4* pv4 = (const float4*)(vb + (half << 5));

  auto STEP = [&](int q, int slot) {
    // consume s_{t-1}: rescale exponent + (in main phase) emit previous output
    float sP = fmaxf(sPrev, FLT_MIN_NORM);     // NaN-guard: stay normal
    int e = ((__float_as_int(sP) >> 23) & 0xFF) - 126;
    float rf = __int_as_float((127 - e) << 23);
    if (q >= WU) {
      float outv = __log2f(sP) * LN2F + S;
      if (q == WU) {
        if ((lane & 31) == 0) Mc[(b << 7) + c] = outv;
      } else {
        if ((lane & 31) == 0) out[outbase + (q - WU) - 1] = outv;
      }
      S += KcH + (float)e * LN2F;
    } else {
      S += (float)e * LN2F;
    }
    // matvec via LDS broadcast
    vb[lane] = v;
    f2 a0; a0.x = 0.f; a0.y = 0.f;
    f2 a1; a1.x = 0.f; a1.y = 0.f;
    #pragma unroll
    for (int k = 0; k < 8; ++k) {
      float4 p = pv4[k];
      f2 plo; plo.x = p.x; plo.y = p.y;
      f2 phi; phi.x = p.z; phi.y = p.w;
      a0 = pk_fma(plo, col2[2*k],   a0);
      a1 = pk_fma(phi, col2[2*k+1], a1);
    }
    float dot = (a0.x + a0.y) + (a1.x + a1.y);
    if (q == WU) dot = isC0 ? v : dot;          // chunk 0: alpha0 = pi (no transition)
    if (q == WU - 8) idx = idxMain;             // prefetch stream jumps to main phase
    uint32_t raw = bl[slot];
    bl[slot] = blin32[idx]; idx += 16;          // prefetch step q+8
    float blf = __int_as_float((raw << shamt) & 0xFFFF0000u);
    v = dot * blf * rf;
    if (q == WU - 1) { if (isC0) { v = pij; S = 0.0f; } }  // reset chunk 0 before main
    float r = dpp_sum32(v);
    sPrev = __int_as_float(__builtin_amdgcn_ds_swizzle(__float_as_int(r), 0x3E0));
  };

  #pragma unroll 1
  for (int m = 0; m < (WU + CL) / 8; ++m) {
    const int q0 = m << 3;
    STEP(q0 + 0, 0); STEP(q0 + 1, 1); STEP(q0 + 2, 2); STEP(q0 + 3, 3);
    STEP(q0 + 4, 4); STEP(q0 + 5, 5); STEP(q0 + 6, 6); STEP(q0 + 7, 7);
  }
  {
    float sP = fmaxf(sPrev, FLT_MIN_NORM);
    float outv = __log2f(sP) * LN2F + S;
    if ((lane & 31) == 0) out[outbase + CL - 1] = outv;
  }
}

// ---------------- K4a: per-subject prefix of chunk offsets (128 chunks)
__global__ void k_stitch(const float* __restrict__ out, const float* __restrict__ Mcc,
                         float* __restrict__ Delta)
{
  __shared__ float w0sum;
  const int b = blockIdx.x;
  const int c = threadIdx.x;     // 0..127 (2 waves)
  float term = 0.0f;
  if (c > 0) term = out[b * TT + (c << 5) - 1] - Mcc[(b << 7) + c];
  for (int off = 1; off < 64; off <<= 1) {
    float up = __shfl_up(term, off);
    if ((c & 63) >= off) term += up;
  }
  if (c == 63) w0sum = term;
  __syncthreads();
  if (c >= 64) term += w0sum;
  Delta[(b << 7) + c] = term;
}

// ---------------- K4b: add offsets
__global__ void k_add(float* __restrict__ out, const float* __restrict__ Delta)
{
  const int i = blockIdx.x * 256 + threadIdx.x;   // i < B*T
  const int b = i >> 12;
  const int t = i & 4095;
  out[i] += Delta[(b << 7) + (t >> 5)];
}

extern "C" void kernel_launch(void* const* d_in, const int* in_sizes, int n_in,
                              void* d_out, int out_size, void* d_ws, size_t ws_size,
                              hipStream_t stream) {
  const float* X   = (const float*)d_in[0];
  const float* tm  = (const float*)d_in[1];
  const float* sp  = (const float*)d_in[2];
  const float* mus = (const float*)d_in[3];
  const float* lv  = (const float*)d_in[4];
  float* out = (float*)d_out;

  char* ws = (char*)d_ws;
  size_t off = 0;
  uint32_t* blin32 = (uint32_t*)(ws + off); off += (size_t)BB * TT * NS * 2 + 4096;
  float* Kcv   = (float*)(ws + off); off += (size_t)BB * CH * 4;
  float* Mcc   = (float*)(ws + off); off += (size_t)BB * CH * 4;
  float* Delta = (float*)(ws + off); off += (size_t)BB * CH * 4;
  float* Amat  = (float*)(ws + off); off += (size_t)NS * NS * 4;
  float* pivec = (float*)(ws + off); off += 256;
  uint32_t* Wp = (uint32_t*)(ws + off); off += (size_t)2048 * 4;
  float* bias  = (float*)(ws + off); off += 256;

  k_pre<<<dim3(1), dim3(1024), 0, stream>>>(tm, sp, mus, lv, Amat, pivec, Wp, bias);
  k_emis<<<dim3(2048), dim3(256), 0, stream>>>(X, Wp, bias, blin32, Kcv);
  k_scan<<<dim3(1024), dim3(256), 0, stream>>>(blin32, Kcv, Amat, pivec, out, Mcc);
  k_stitch<<<dim3(BB), dim3(128), 0, stream>>>(out, Mcc, Delta);
  k_add<<<dim3((BB * TT) / 256), dim3(256), 0, stream>>>(out, Delta);
}

// Round 10
// 47.282 us; speedup vs baseline: 1.6337x; 1.1463x over previous
//
#include <hip/hip_runtime.h>
#include <hip/hip_bf16.h>
#include <stdint.h>

#define BB 64
#define TT 4096
#define NS 32
#define DD 64
#define CH 256     // chunks per subject
#define CL 16      // chunk length
#define WU 8       // warmup steps (Birkhoff tau~0.15/step -> ~3e-7 after 8)
#define NSTEPS (WU + CL)
#define LOG2PI 1.8378770664093453f
#define LN2F 0.6931471805599453f
#define FLT_MIN_NORM 1.175494350822288e-38f

typedef float f32x16 __attribute__((ext_vector_type(16)));
typedef __bf16 bf16x8 __attribute__((ext_vector_type(8)));

__device__ __forceinline__ uint32_t cvt_pk_bf16(float lo, float hi) {
  uint32_t d;
  asm("v_cvt_pk_bf16_f32 %0, %1, %2" : "=v"(d) : "v"(lo), "v"(hi));
  return d;
}

// max over all 64 lanes; result valid in lane 63
__device__ __forceinline__ float dpp_max64(float v) {
  float r = v; int x;
  x = __builtin_amdgcn_update_dpp(__float_as_int(r), __float_as_int(r), 0x111, 0xF, 0xF, false); r = fmaxf(r, __int_as_float(x));
  x = __builtin_amdgcn_update_dpp(__float_as_int(r), __float_as_int(r), 0x112, 0xF, 0xF, false); r = fmaxf(r, __int_as_float(x));
  x = __builtin_amdgcn_update_dpp(__float_as_int(r), __float_as_int(r), 0x114, 0xF, 0xF, false); r = fmaxf(r, __int_as_float(x));
  x = __builtin_amdgcn_update_dpp(__float_as_int(r), __float_as_int(r), 0x118, 0xF, 0xF, false); r = fmaxf(r, __int_as_float(x));
  x = __builtin_amdgcn_update_dpp(__float_as_int(r), __float_as_int(r), 0x142, 0xF, 0xF, false); r = fmaxf(r, __int_as_float(x));
  x = __builtin_amdgcn_update_dpp(__float_as_int(r), __float_as_int(r), 0x143, 0xF, 0xF, false); r = fmaxf(r, __int_as_float(x));
  return r;
}

// slot bijection shared by: MFMA C-row layout (HW-verified), scan A^T-frag,
// scan B-frag, blin state pairing, pivec reset.
//   state(h, r) = (r&3) + 8*((r>>2)&1) + 4*h + 16*(r>>3),  r in [0,16)

// ---------------- K1: preprocess
// Amat softmax -> LDS -> A^T MFMA fragment table Af.
// Af[l*8 + m*4 + p] = pack_bf16(A[s(2p)][j], A[s(2p+1)][j]), l=(j,h), frag m.
__global__ __launch_bounds__(1024) void k_pre(
    const float* __restrict__ tm, const float* __restrict__ sp,
    const float* __restrict__ mus, const float* __restrict__ lv,
    float* __restrict__ pivec, uint32_t* __restrict__ Wp,
    float* __restrict__ bias, uint32_t* __restrict__ Af)
{
  __shared__ float As[32][32];
  const int tid = threadIdx.x;       // 0..1023
  const int row = tid >> 5;          // 0..31
  const int col = tid & 31;          // 0..31

  // --- transition-matrix row softmax -> LDS
  {
    float v = tm[row * 32 + col];
    float m = v;
    #pragma unroll
    for (int mask = 16; mask; mask >>= 1) m = fmaxf(m, __shfl_xor(m, mask));
    float e = __expf(v - m);
    float s = e;
    #pragma unroll
    for (int mask = 16; mask; mask >>= 1) s += __shfl_xor(s, mask);
    As[row][col] = e / s;
  }

  // --- state-prior softmax (lanes 0..31 of wave 0)
  if (tid < 32) {
    float v = sp[tid];
    float m = v;
    #pragma unroll
    for (int mask = 16; mask; mask >>= 1) m = fmaxf(m, __shfl_xor(m, mask));
    float e = __expf(v - m);
    float s = e;
    #pragma unroll
    for (int mask = 16; mask; mask >>= 1) s += __shfl_xor(s, mask);
    pivec[tid] = e / s;
  }

  // --- Wp fragment table for k_emis (bf16 pairs)
  #pragma unroll
  for (int hh = 0; hh < 2; ++hh) {
    int d = col + (hh << 5);             // 0..63
    float iv = __expf(-lv[row * 64 + d]);
    uint32_t w = cvt_pk_bf16(-0.5f * iv, mus[row * 64 + d] * iv);
    int kk = d >> 3, h2 = (d >> 2) & 1, j = d & 3;
    Wp[(((row << 1) + h2) * 8 + kk) * 4 + j] = w;
  }

  // --- bias[n]
  {
    float s2 = 0.f, slv = 0.f;
    #pragma unroll
    for (int h = 0; h < 2; ++h) {
      int d = col + h * 32;
      float m_ = mus[row * 64 + d];
      float l_ = lv[row * 64 + d];
      s2 = fmaf(m_ * m_, __expf(-l_), s2);
      slv += l_;
    }
    #pragma unroll
    for (int mask = 16; mask; mask >>= 1) {
      s2  += __shfl_xor(s2, mask);
      slv += __shfl_xor(slv, mask);
    }
    if (col == 0) bias[row] = -0.5f * (s2 + slv + (float)DD * LOG2PI);
  }

  __syncthreads();

  // --- A^T fragment table (scan MFMA A-operand)
  if (tid < 512) {
    int l = tid >> 3, s = tid & 7;
    int m = s >> 2, p = s & 3;
    int j = l & 31, hh = l >> 5;
    int r0 = 2 * p, r1 = r0 + 1;
    int s0 = (r0 & 3) + 8 * ((r0 >> 2) & 1) + 4 * hh + 16 * m;
    int s1 = (r1 & 3) + 8 * ((r1 >> 2) & 1) + 4 * hh + 16 * m;
    Af[(l << 3) + (m << 2) + p] = cvt_pk_bf16(As[s0][j], As[s1][j]);
  }
}

// ---------------- K2: emission via MFMA -> blin (bf16, per-16-t-chunk max)
// One wave = 32 t-rows x 32 states (2 chunks of CL=16); K=128 ([x^2; x]).
// C layout (HW-verified): col=lane&31, row=(reg&3)+8*(reg>>2)+4*(lane>>5);
// reg-halves 0..7 / 8..15 split exactly at t-row 16 -> two chunk maxes.
__global__ __launch_bounds__(256, 4) void k_emis(
    const float* __restrict__ Xg,
    const uint32_t* __restrict__ Wp,
    const float* __restrict__ bias,
    uint32_t* __restrict__ blin32,
    float* __restrict__ Kc)
{
  const int tid = threadIdx.x;
  const int l   = tid & 63;
  const int w   = tid >> 6;            // wave 0..3
  const int bid = blockIdx.x;          // 0..2047
  const int b   = bid >> 5;
  const int cc  = bid & 31;
  const int chunk = (cc << 2) + w;     // 32-t window 0..127
  const int t0w = chunk << 5;
  const int n   = l & 31;
  const int h   = l >> 5;

  uint4 wf[8];
  const uint4* wp4 = (const uint4*)(Wp + ((n << 1) + h) * 32);
  #pragma unroll
  for (int kk = 0; kk < 8; ++kk) wf[kk] = wp4[kk];

  const float* xr = Xg + (size_t)(b * TT + t0w + n) * DD + (h << 2);

  f32x16 acc;
  #pragma unroll
  for (int r = 0; r < 16; ++r) acc[r] = 0.0f;

  #pragma unroll
  for (int kk = 0; kk < 8; ++kk) {
    float4 x4 = *(const float4*)(xr + (kk << 3));
    uint4 au;
    au.x = cvt_pk_bf16(x4.x * x4.x, x4.x);
    au.y = cvt_pk_bf16(x4.y * x4.y, x4.y);
    au.z = cvt_pk_bf16(x4.z * x4.z, x4.z);
    au.w = cvt_pk_bf16(x4.w * x4.w, x4.w);
    bf16x8 af = __builtin_bit_cast(bf16x8, au);
    bf16x8 bf = __builtin_bit_cast(bf16x8, wf[kk]);
    acc = __builtin_amdgcn_mfma_f32_32x32x16_bf16(af, bf, acc, 0, 0, 0);
  }

  const float bn = bias[n];
  float lb[16];
  float m0 = -1e30f, m1 = -1e30f;
  #pragma unroll
  for (int r = 0; r < 16; ++r) {
    lb[r] = acc[r] + bn;
    if (r < 8) m0 = fmaxf(m0, lb[r]); else m1 = fmaxf(m1, lb[r]);
  }
  m0 = dpp_max64(m0);
  m1 = dpp_max64(m1);
  const float Km0 = __int_as_float(__builtin_amdgcn_readlane(__float_as_int(m0), 63));
  const float Km1 = __int_as_float(__builtin_amdgcn_readlane(__float_as_int(m1), 63));
  if (l == 0) {
    Kc[(b << 8) + (chunk << 1)]     = Km0;
    Kc[(b << 8) + (chunk << 1) + 1] = Km1;
  }

  const int tb = b * TT + t0w;
  #pragma unroll
  for (int r = 0; r < 16; ++r) {
    float e = __expf(lb[r] - ((r < 8) ? Km0 : Km1));
    int nb = __builtin_amdgcn_update_dpp(0, __float_as_int(e), 0xB1, 0xF, 0xF, true); // lane^1
    uint32_t pk = cvt_pk_bf16(e, __int_as_float(nb));   // lo = even n, hi = odd n
    const int trow = (r & 3) + ((r >> 2) << 3) + (h << 2);
    if ((l & 1) == 0)
      blin32[(size_t)(tb + trow) * 16 + (n >> 1)] = pk;
  }
}

// ---------------- K3: MFMA-batched linear-space scan
// One wave = 32 chunks (lane col = chunk; 16 C-regs = that chunk's states).
// Step: V' = (A^T (rf*V)) . b_t. Slot bijection == C-row layout -> MFMA
// output regs feed the next B-frag directly (no cross-lane movement).
__global__ __launch_bounds__(256) void k_scan(
    const uint32_t* __restrict__ blin32,
    const float* __restrict__ Kc,
    const uint32_t* __restrict__ Af,
    const float* __restrict__ pivec,
    float* __restrict__ out,
    float* __restrict__ Mc)
{
  const int tid = threadIdx.x;
  const int l   = tid & 63;
  const int w   = tid >> 6;
  const int g   = (blockIdx.x << 2) + w;   // 0..511
  const int b   = g >> 3;
  const int cb  = g & 7;
  const int col = l & 31;
  const int h   = l >> 5;
  const int c   = (cb << 5) + col;         // chunk 0..255
  const bool isC0 = (c == 0);

  const uint4 af0u = *(const uint4*)(Af + (l << 3));
  const uint4 af1u = *(const uint4*)(Af + (l << 3) + 4);
  const bf16x8 af0 = __builtin_bit_cast(bf16x8, af0u);
  const bf16x8 af1 = __builtin_bit_cast(bf16x8, af1u);

  const float KcH = Kc[(b << 8) + c];
  const int outbase = b * TT + (c << 4);
  const int base0 = (b * TT + (c << 4) - WU) * 16 + (h << 1);
  const int baseClamp = b * TT * 16 + (h << 1);

  uint32_t blA[8], blB[8];
  #define LOADB(Q, B) { \
    int i0 = base0 + (Q) * 16; if (i0 < baseClamp) i0 = baseClamp; \
    const uint32_t* p = blin32 + i0; \
    uint2 u0 = *(const uint2*)(p); \
    uint2 u1 = *(const uint2*)(p + 4); \
    uint2 u2 = *(const uint2*)(p + 8); \
    uint2 u3 = *(const uint2*)(p + 12); \
    B[0]=u0.x; B[1]=u0.y; B[2]=u1.x; B[3]=u1.y; \
    B[4]=u2.x; B[5]=u2.y; B[6]=u3.x; B[7]=u3.y; }
  LOADB(0, blA)
  LOADB(1, blB)

  f32x16 zv;
  #pragma unroll
  for (int r = 0; r < 16; ++r) zv[r] = 0.0f;

  float v[16];
  #pragma unroll
  for (int r = 0; r < 16; ++r) v[r] = 1.0f;
  float S = 0.0f, sPrev = 1.0f;

  #define SCAN_STEP(Q, CUR) { \
    float sP = fmaxf(sPrev, FLT_MIN_NORM); \
    int e = ((__float_as_int(sP) >> 23) & 0xFF) - 126; \
    float rf = __int_as_float((127 - e) << 23); \
    if ((Q) >= WU) { \
      float outv = __log2f(sP) * LN2F + S; \
      if ((Q) == WU) { if (h == 0) Mc[(b << 8) + c] = outv; } \
      else           { if (h == 0) out[outbase + (Q) - WU - 1] = outv; } \
      S += KcH + (float)e * LN2F; \
    } else { S += (float)e * LN2F; } \
    float vr[16]; \
    _Pragma("unroll") \
    for (int r = 0; r < 16; ++r) vr[r] = v[r] * rf; \
    uint32_t p2[8]; \
    _Pragma("unroll") \
    for (int i = 0; i < 8; ++i) p2[i] = cvt_pk_bf16(vr[2*i], vr[2*i+1]); \
    uint4 b0u; b0u.x = p2[0]; b0u.y = p2[1]; b0u.z = p2[2]; b0u.w = p2[3]; \
    uint4 b1u; b1u.x = p2[4]; b1u.y = p2[5]; b1u.z = p2[6]; b1u.w = p2[7]; \
    f32x16 acc = __builtin_amdgcn_mfma_f32_32x32x16_bf16(af0, __builtin_bit_cast(bf16x8, b0u), zv, 0, 0, 0); \
    acc = __builtin_amdgcn_mfma_f32_32x32x16_bf16(af1, __builtin_bit_cast(bf16x8, b1u), acc, 0, 0, 0); \
    _Pragma("unroll") \
    for (int i = 0; i < 8; ++i) { \
      float blo = __int_as_float(CUR[i] << 16); \
      float bhi = __int_as_float(CUR[i] & 0xFFFF0000u); \
      float d0 = acc[2*i], d1 = acc[2*i+1]; \
      if ((Q) == WU) { if (isC0) { d0 = vr[2*i]; d1 = vr[2*i+1]; } } \
      v[2*i]   = d0 * blo; \
      v[2*i+1] = d1 * bhi; \
    } \
    if ((Q) == WU - 1) { \
      if (isC0) { \
        _Pragma("unroll") \
        for (int r = 0; r < 16; ++r) \
          v[r] = pivec[(r & 3) + 8 * ((r >> 2) & 1) + (h << 2) + ((r >> 3) << 4)]; \
        S = 0.0f; \
      } \
    } \
    float s8[8]; \
    _Pragma("unroll") \
    for (int i = 0; i < 8; ++i) s8[i] = v[2*i] + v[2*i+1]; \
    float s4a = s8[0] + s8[1], s4b = s8[2] + s8[3]; \
    float s4c = s8[4] + s8[5], s4d = s8[6] + s8[7]; \
    float s = (s4a + s4b) + (s4c + s4d); \
    s += __shfl_xor(s, 32); \
    sPrev = s; \
    if ((Q) + 2 < NSTEPS) LOADB((Q) + 2, CUR) \
  }

  #pragma unroll
  for (int m = 0; m < NSTEPS / 2; ++m) {
    SCAN_STEP(2 * m,     blA)
    SCAN_STEP(2 * m + 1, blB)
  }
  #undef SCAN_STEP
  #undef LOADB

  {
    float sP = fmaxf(sPrev, FLT_MIN_NORM);
    if (h == 0) out[outbase + CL - 1] = __log2f(sP) * LN2F + S;
  }
}

// ---------------- K4a: per-subject prefix of chunk offsets (256 chunks)
__global__ void k_stitch(const float* __restrict__ out, const float* __restrict__ Mcc,
                         float* __restrict__ Delta)
{
  __shared__ float wsum[4];
  const int b  = blockIdx.x;
  const int c  = threadIdx.x;     // 0..255 (4 waves)
  const int wv = c >> 6, ln = c & 63;
  float term = 0.0f;
  if (c > 0) term = out[b * TT + (c << 4) - 1] - Mcc[(b << 8) + c];
  for (int off = 1; off < 64; off <<= 1) {
    float up = __shfl_up(term, off);
    if (ln >= off) term += up;
  }
  if (ln == 63) wsum[wv] = term;
  __syncthreads();
  float add = 0.0f;
  for (int i = 0; i < wv; ++i) add += wsum[i];
  Delta[(b << 8) + c] = term + add;
}

// ---------------- K4b: add offsets
__global__ void k_add(float* __restrict__ out, const float* __restrict__ Delta)
{
  const int i = blockIdx.x * 256 + threadIdx.x;   // i < B*T
  const int b = i >> 12;
  const int t = i & 4095;
  out[i] += Delta[(b << 8) + (t >> 4)];
}

extern "C" void kernel_launch(void* const* d_in, const int* in_sizes, int n_in,
                              void* d_out, int out_size, void* d_ws, size_t ws_size,
                              hipStream_t stream) {
  const float* X   = (const float*)d_in[0];
  const float* tm  = (const float*)d_in[1];
  const float* sp  = (const float*)d_in[2];
  const float* mus = (const float*)d_in[3];
  const float* lv  = (const float*)d_in[4];
  float* out = (float*)d_out;

  char* ws = (char*)d_ws;
  size_t off = 0;
  uint32_t* blin32 = (uint32_t*)(ws + off); off += (size_t)BB * TT * NS * 2 + 4096;
  float* Kcv   = (float*)(ws + off); off += (size_t)BB * CH * 4;
  float* Mcc   = (float*)(ws + off); off += (size_t)BB * CH * 4;
  float* Delta = (float*)(ws + off); off += (size_t)BB * CH * 4;
  float* pivec = (float*)(ws + off); off += 256;
  uint32_t* Wp = (uint32_t*)(ws + off); off += (size_t)2048 * 4;
  float* bias  = (float*)(ws + off); off += 256;
  uint32_t* Af = (uint32_t*)(ws + off); off += (size_t)512 * 4;

  k_pre<<<dim3(1), dim3(1024), 0, stream>>>(tm, sp, mus, lv, pivec, Wp, bias, Af);
  k_emis<<<dim3(2048), dim3(256), 0, stream>>>(X, Wp, bias, blin32, Kcv);
  k_scan<<<dim3(128), dim3(256), 0, stream>>>(blin32, Kcv, Af, pivec, out, Mcc);
  k_stitch<<<dim3(BB), dim3(256), 0, stream>>>(out, Mcc, Delta);
  k_add<<<dim3((BB * TT) / 256), dim3(256), 0, stream>>>(out, Delta);
}

// Round 11
// 47.013 us; speedup vs baseline: 1.6431x; 1.0057x over previous
//
#include <hip/hip_runtime.h>
#include <hip/hip_bf16.h>
#include <stdint.h>

#define BB 64
#define TT 4096
#define NS 32
#define DD 64
#define CH 256     // chunks per subject
#define CL 16      // chunk length
#define WU 8       // warmup steps (Birkhoff tau~0.15/step -> ~3e-7 after 8)
#define NSTEPS (WU + CL)
#define LOG2PI 1.8378770664093453f
#define LN2F 0.6931471805599453f
#define FLT_MIN_NORM 1.175494350822288e-38f

typedef float f32x16 __attribute__((ext_vector_type(16)));
typedef __bf16 bf16x8 __attribute__((ext_vector_type(8)));

__device__ __forceinline__ uint32_t cvt_pk_bf16(float lo, float hi) {
  uint32_t d;
  asm("v_cvt_pk_bf16_f32 %0, %1, %2" : "=v"(d) : "v"(lo), "v"(hi));
  return d;
}

// max over all 64 lanes; result valid in lane 63
__device__ __forceinline__ float dpp_max64(float v) {
  float r = v; int x;
  x = __builtin_amdgcn_update_dpp(__float_as_int(r), __float_as_int(r), 0x111, 0xF, 0xF, false); r = fmaxf(r, __int_as_float(x));
  x = __builtin_amdgcn_update_dpp(__float_as_int(r), __float_as_int(r), 0x112, 0xF, 0xF, false); r = fmaxf(r, __int_as_float(x));
  x = __builtin_amdgcn_update_dpp(__float_as_int(r), __float_as_int(r), 0x114, 0xF, 0xF, false); r = fmaxf(r, __int_as_float(x));
  x = __builtin_amdgcn_update_dpp(__float_as_int(r), __float_as_int(r), 0x118, 0xF, 0xF, false); r = fmaxf(r, __int_as_float(x));
  x = __builtin_amdgcn_update_dpp(__float_as_int(r), __float_as_int(r), 0x142, 0xF, 0xF, false); r = fmaxf(r, __int_as_float(x));
  x = __builtin_amdgcn_update_dpp(__float_as_int(r), __float_as_int(r), 0x143, 0xF, 0xF, false); r = fmaxf(r, __int_as_float(x));
  return r;
}

// slot bijection shared by: MFMA C-row layout (HW-verified), scan A^T-frag,
// scan B-frag, blin state pairing, pivec reset.
//   state(h, r) = (r&3) + 8*((r>>2)&1) + 4*h + 16*(r>>3),  r in [0,16)

// ---------------- K1: preprocess
__global__ __launch_bounds__(1024) void k_pre(
    const float* __restrict__ tm, const float* __restrict__ sp,
    const float* __restrict__ mus, const float* __restrict__ lv,
    float* __restrict__ pivec, uint32_t* __restrict__ Wp,
    float* __restrict__ bias, uint32_t* __restrict__ Af)
{
  __shared__ float As[32][32];
  const int tid = threadIdx.x;       // 0..1023
  const int row = tid >> 5;          // 0..31
  const int col = tid & 31;          // 0..31

  // --- transition-matrix row softmax -> LDS
  {
    float v = tm[row * 32 + col];
    float m = v;
    #pragma unroll
    for (int mask = 16; mask; mask >>= 1) m = fmaxf(m, __shfl_xor(m, mask));
    float e = __expf(v - m);
    float s = e;
    #pragma unroll
    for (int mask = 16; mask; mask >>= 1) s += __shfl_xor(s, mask);
    As[row][col] = e / s;
  }

  // --- state-prior softmax (lanes 0..31 of wave 0)
  if (tid < 32) {
    float v = sp[tid];
    float m = v;
    #pragma unroll
    for (int mask = 16; mask; mask >>= 1) m = fmaxf(m, __shfl_xor(m, mask));
    float e = __expf(v - m);
    float s = e;
    #pragma unroll
    for (int mask = 16; mask; mask >>= 1) s += __shfl_xor(s, mask);
    pivec[tid] = e / s;
  }

  // --- Wp fragment table for k_emis (bf16 pairs)
  #pragma unroll
  for (int hh = 0; hh < 2; ++hh) {
    int d = col + (hh << 5);             // 0..63
    float iv = __expf(-lv[row * 64 + d]);
    uint32_t w = cvt_pk_bf16(-0.5f * iv, mus[row * 64 + d] * iv);
    int kk = d >> 3, h2 = (d >> 2) & 1, j = d & 3;
    Wp[(((row << 1) + h2) * 8 + kk) * 4 + j] = w;
  }

  // --- bias[n]
  {
    float s2 = 0.f, slv = 0.f;
    #pragma unroll
    for (int h = 0; h < 2; ++h) {
      int d = col + h * 32;
      float m_ = mus[row * 64 + d];
      float l_ = lv[row * 64 + d];
      s2 = fmaf(m_ * m_, __expf(-l_), s2);
      slv += l_;
    }
    #pragma unroll
    for (int mask = 16; mask; mask >>= 1) {
      s2  += __shfl_xor(s2, mask);
      slv += __shfl_xor(slv, mask);
    }
    if (col == 0) bias[row] = -0.5f * (s2 + slv + (float)DD * LOG2PI);
  }

  __syncthreads();

  // --- A^T fragment table (scan MFMA A-operand)
  if (tid < 512) {
    int l = tid >> 3, s = tid & 7;
    int m = s >> 2, p = s & 3;
    int j = l & 31, hh = l >> 5;
    int r0 = 2 * p, r1 = r0 + 1;
    int s0 = (r0 & 3) + 8 * ((r0 >> 2) & 1) + 4 * hh + 16 * m;
    int s1 = (r1 & 3) + 8 * ((r1 >> 2) & 1) + 4 * hh + 16 * m;
    Af[(l << 3) + (m << 2) + p] = cvt_pk_bf16(As[s0][j], As[s1][j]);
  }
}

// ---------------- K2: emission via MFMA -> blin (bf16, per-16-t-chunk max)
// One wave = 32 t-rows x 32 states (2 chunks of CL=16); K=128 ([x^2; x]).
// R11: all 8 X loads issued upfront into named regs (MLP: 8 outstanding
// 16B/lane loads per wave) before the cvt->MFMA chain consumes them.
__global__ __launch_bounds__(256, 4) void k_emis(
    const float* __restrict__ Xg,
    const uint32_t* __restrict__ Wp,
    const float* __restrict__ bias,
    uint32_t* __restrict__ blin32,
    float* __restrict__ Kc)
{
  const int tid = threadIdx.x;
  const int l   = tid & 63;
  const int w   = tid >> 6;            // wave 0..3
  const int bid = blockIdx.x;          // 0..2047
  const int b   = bid >> 5;
  const int cc  = bid & 31;
  const int chunk = (cc << 2) + w;     // 32-t window 0..127
  const int t0w = chunk << 5;
  const int n   = l & 31;
  const int h   = l >> 5;

  const float* xr = Xg + (size_t)(b * TT + t0w + n) * DD + (h << 2);

  // --- issue ALL X loads first (8 outstanding per lane)
  float4 x0 = *(const float4*)(xr);
  float4 x1 = *(const float4*)(xr + 8);
  float4 x2 = *(const float4*)(xr + 16);
  float4 x3 = *(const float4*)(xr + 24);
  float4 x4 = *(const float4*)(xr + 32);
  float4 x5 = *(const float4*)(xr + 40);
  float4 x6 = *(const float4*)(xr + 48);
  float4 x7 = *(const float4*)(xr + 56);

  uint4 wf[8];
  const uint4* wp4 = (const uint4*)(Wp + ((n << 1) + h) * 32);
  #pragma unroll
  for (int kk = 0; kk < 8; ++kk) wf[kk] = wp4[kk];

  f32x16 acc;
  #pragma unroll
  for (int r = 0; r < 16; ++r) acc[r] = 0.0f;

  #define EMIT(KK, XV) { \
    uint4 au; \
    au.x = cvt_pk_bf16(XV.x * XV.x, XV.x); \
    au.y = cvt_pk_bf16(XV.y * XV.y, XV.y); \
    au.z = cvt_pk_bf16(XV.z * XV.z, XV.z); \
    au.w = cvt_pk_bf16(XV.w * XV.w, XV.w); \
    bf16x8 af_ = __builtin_bit_cast(bf16x8, au); \
    bf16x8 bf_ = __builtin_bit_cast(bf16x8, wf[KK]); \
    acc = __builtin_amdgcn_mfma_f32_32x32x16_bf16(af_, bf_, acc, 0, 0, 0); }
  EMIT(0, x0) EMIT(1, x1) EMIT(2, x2) EMIT(3, x3)
  EMIT(4, x4) EMIT(5, x5) EMIT(6, x6) EMIT(7, x7)
  #undef EMIT

  const float bn = bias[n];
  float lb[16];
  float m0 = -1e30f, m1 = -1e30f;
  #pragma unroll
  for (int r = 0; r < 16; ++r) {
    lb[r] = acc[r] + bn;
    if (r < 8) m0 = fmaxf(m0, lb[r]); else m1 = fmaxf(m1, lb[r]);
  }
  m0 = dpp_max64(m0);
  m1 = dpp_max64(m1);
  const float Km0 = __int_as_float(__builtin_amdgcn_readlane(__float_as_int(m0), 63));
  const float Km1 = __int_as_float(__builtin_amdgcn_readlane(__float_as_int(m1), 63));
  if (l == 0) {
    Kc[(b << 8) + (chunk << 1)]     = Km0;
    Kc[(b << 8) + (chunk << 1) + 1] = Km1;
  }

  const int tb = b * TT + t0w;
  #pragma unroll
  for (int r = 0; r < 16; ++r) {
    float e = __expf(lb[r] - ((r < 8) ? Km0 : Km1));
    int nb = __builtin_amdgcn_update_dpp(0, __float_as_int(e), 0xB1, 0xF, 0xF, true); // lane^1
    uint32_t pk = cvt_pk_bf16(e, __int_as_float(nb));   // lo = even n, hi = odd n
    const int trow = (r & 3) + ((r >> 2) << 3) + (h << 2);
    if ((l & 1) == 0)
      blin32[(size_t)(tb + trow) * 16 + (n >> 1)] = pk;
  }
}

// ---------------- K3: MFMA-batched linear-space scan
// One wave = 32 chunks (lane col = chunk; 16 C-regs = that chunk's states).
// Step: V' = (A^T (rf*V)) . b_t. Slot bijection == C-row layout -> MFMA
// output regs feed the next B-frag directly (no cross-lane movement).
__global__ __launch_bounds__(256) void k_scan(
    const uint32_t* __restrict__ blin32,
    const float* __restrict__ Kc,
    const uint32_t* __restrict__ Af,
    const float* __restrict__ pivec,
    float* __restrict__ out,
    float* __restrict__ Mc)
{
  const int tid = threadIdx.x;
  const int l   = tid & 63;
  const int w   = tid >> 6;
  const int g   = (blockIdx.x << 2) + w;   // 0..511
  const int b   = g >> 3;
  const int cb  = g & 7;
  const int col = l & 31;
  const int h   = l >> 5;
  const int c   = (cb << 5) + col;         // chunk 0..255
  const bool isC0 = (c == 0);

  const uint4 af0u = *(const uint4*)(Af + (l << 3));
  const uint4 af1u = *(const uint4*)(Af + (l << 3) + 4);
  const bf16x8 af0 = __builtin_bit_cast(bf16x8, af0u);
  const bf16x8 af1 = __builtin_bit_cast(bf16x8, af1u);

  const float KcH = Kc[(b << 8) + c];
  const int outbase = b * TT + (c << 4);
  const int base0 = (b * TT + (c << 4) - WU) * 16 + (h << 1);
  const int baseClamp = b * TT * 16 + (h << 1);

  uint32_t blA[8], blB[8];
  #define LOADB(Q, B) { \
    int i0 = base0 + (Q) * 16; if (i0 < baseClamp) i0 = baseClamp; \
    const uint32_t* p = blin32 + i0; \
    uint2 u0 = *(const uint2*)(p); \
    uint2 u1 = *(const uint2*)(p + 4); \
    uint2 u2 = *(const uint2*)(p + 8); \
    uint2 u3 = *(const uint2*)(p + 12); \
    B[0]=u0.x; B[1]=u0.y; B[2]=u1.x; B[3]=u1.y; \
    B[4]=u2.x; B[5]=u2.y; B[6]=u3.x; B[7]=u3.y; }
  LOADB(0, blA)
  LOADB(1, blB)

  f32x16 zv;
  #pragma unroll
  for (int r = 0; r < 16; ++r) zv[r] = 0.0f;

  float v[16];
  #pragma unroll
  for (int r = 0; r < 16; ++r) v[r] = 1.0f;
  float S = 0.0f, sPrev = 1.0f;

  #define SCAN_STEP(Q, CUR) { \
    float sP = fmaxf(sPrev, FLT_MIN_NORM); \
    int e = ((__float_as_int(sP) >> 23) & 0xFF) - 126; \
    float rf = __int_as_float((127 - e) << 23); \
    if ((Q) >= WU) { \
      float outv = __log2f(sP) * LN2F + S; \
      if ((Q) == WU) { if (h == 0) Mc[(b << 8) + c] = outv; } \
      else           { if (h == 0) out[outbase + (Q) - WU - 1] = outv; } \
      S += KcH + (float)e * LN2F; \
    } else { S += (float)e * LN2F; } \
    float vr[16]; \
    _Pragma("unroll") \
    for (int r = 0; r < 16; ++r) vr[r] = v[r] * rf; \
    uint32_t p2[8]; \
    _Pragma("unroll") \
    for (int i = 0; i < 8; ++i) p2[i] = cvt_pk_bf16(vr[2*i], vr[2*i+1]); \
    uint4 b0u; b0u.x = p2[0]; b0u.y = p2[1]; b0u.z = p2[2]; b0u.w = p2[3]; \
    uint4 b1u; b1u.x = p2[4]; b1u.y = p2[5]; b1u.z = p2[6]; b1u.w = p2[7]; \
    f32x16 acc = __builtin_amdgcn_mfma_f32_32x32x16_bf16(af0, __builtin_bit_cast(bf16x8, b0u), zv, 0, 0, 0); \
    acc = __builtin_amdgcn_mfma_f32_32x32x16_bf16(af1, __builtin_bit_cast(bf16x8, b1u), acc, 0, 0, 0); \
    _Pragma("unroll") \
    for (int i = 0; i < 8; ++i) { \
      float blo = __int_as_float(CUR[i] << 16); \
      float bhi = __int_as_float(CUR[i] & 0xFFFF0000u); \
      float d0 = acc[2*i], d1 = acc[2*i+1]; \
      if ((Q) == WU) { if (isC0) { d0 = vr[2*i]; d1 = vr[2*i+1]; } } \
      v[2*i]   = d0 * blo; \
      v[2*i+1] = d1 * bhi; \
    } \
    if ((Q) == WU - 1) { \
      if (isC0) { \
        _Pragma("unroll") \
        for (int r = 0; r < 16; ++r) \
          v[r] = pivec[(r & 3) + 8 * ((r >> 2) & 1) + (h << 2) + ((r >> 3) << 4)]; \
        S = 0.0f; \
      } \
    } \
    float s8[8]; \
    _Pragma("unroll") \
    for (int i = 0; i < 8; ++i) s8[i] = v[2*i] + v[2*i+1]; \
    float s4a = s8[0] + s8[1], s4b = s8[2] + s8[3]; \
    float s4c = s8[4] + s8[5], s4d = s8[6] + s8[7]; \
    float s = (s4a + s4b) + (s4c + s4d); \
    s += __shfl_xor(s, 32); \
    sPrev = s; \
    if ((Q) + 2 < NSTEPS) LOADB((Q) + 2, CUR) \
  }

  #pragma unroll
  for (int m = 0; m < NSTEPS / 2; ++m) {
    SCAN_STEP(2 * m,     blA)
    SCAN_STEP(2 * m + 1, blB)
  }
  #undef SCAN_STEP
  #undef LOADB

  {
    float sP = fmaxf(sPrev, FLT_MIN_NORM);
    if (h == 0) out[outbase + CL - 1] = __log2f(sP) * LN2F + S;
  }
}

// ---------------- K4a: per-subject prefix of chunk offsets (256 chunks)
__global__ void k_stitch(const float* __restrict__ out, const float* __restrict__ Mcc,
                         float* __restrict__ Delta)
{
  __shared__ float wsum[4];
  const int b  = blockIdx.x;
  const int c  = threadIdx.x;     // 0..255 (4 waves)
  const int wv = c >> 6, ln = c & 63;
  float term = 0.0f;
  if (c > 0) term = out[b * TT + (c << 4) - 1] - Mcc[(b << 8) + c];
  for (int off = 1; off < 64; off <<= 1) {
    float up = __shfl_up(term, off);
    if (ln >= off) term += up;
  }
  if (ln == 63) wsum[wv] = term;
  __syncthreads();
  float add = 0.0f;
  for (int i = 0; i < wv; ++i) add += wsum[i];
  Delta[(b << 8) + c] = term + add;
}

// ---------------- K4b: add offsets
__global__ void k_add(float* __restrict__ out, const float* __restrict__ Delta)
{
  const int i = blockIdx.x * 256 + threadIdx.x;   // i < B*T
  const int b = i >> 12;
  const int t = i & 4095;
  out[i] += Delta[(b << 8) + (t >> 4)];
}

extern "C" void kernel_launch(void* const* d_in, const int* in_sizes, int n_in,
                              void* d_out, int out_size, void* d_ws, size_t ws_size,
                              hipStream_t stream) {
  const float* X   = (const float*)d_in[0];
  const float* tm  = (const float*)d_in[1];
  const float* sp  = (const float*)d_in[2];
  const float* mus = (const float*)d_in[3];
  const float* lv  = (const float*)d_in[4];
  float* out = (float*)d_out;

  char* ws = (char*)d_ws;
  size_t off = 0;
  uint32_t* blin32 = (uint32_t*)(ws + off); off += (size_t)BB * TT * NS * 2 + 4096;
  float* Kcv   = (float*)(ws + off); off += (size_t)BB * CH * 4;
  float* Mcc   = (float*)(ws + off); off += (size_t)BB * CH * 4;
  float* Delta = (float*)(ws + off); off += (size_t)BB * CH * 4;
  float* pivec = (float*)(ws + off); off += 256;
  uint32_t* Wp = (uint32_t*)(ws + off); off += (size_t)2048 * 4;
  float* bias  = (float*)(ws + off); off += 256;
  uint32_t* Af = (uint32_t*)(ws + off); off += (size_t)512 * 4;

  k_pre<<<dim3(1), dim3(1024), 0, stream>>>(tm, sp, mus, lv, pivec, Wp, bias, Af);
  k_emis<<<dim3(2048), dim3(256), 0, stream>>>(X, Wp, bias, blin32, Kcv);
  k_scan<<<dim3(128), dim3(256), 0, stream>>>(blin32, Kcv, Af, pivec, out, Mcc);
  k_stitch<<<dim3(BB), dim3(256), 0, stream>>>(out, Mcc, Delta);
  k_add<<<dim3((BB * TT) / 256), dim3(256), 0, stream>>>(out, Delta);
}

// Round 13
// 46.368 us; speedup vs baseline: 1.6659x; 1.0139x over previous
//
#include <hip/hip_runtime.h>
#include <hip/hip_bf16.h>
#include <stdint.h>

#define BB 64
#define TT 4096
#define NS 32
#define DD 64
#define CH 256     // chunks per subject
#define CL 16      // chunk length
#define WU 8       // warmup steps (Birkhoff tau~0.15/step -> ~3e-7 after 8)
#define NSTEPS (WU + CL)
#define LOG2PI 1.8378770664093453f
#define LN2F 0.6931471805599453f
#define FLT_MIN_NORM 1.175494350822288e-38f

typedef float f32x16 __attribute__((ext_vector_type(16)));
typedef __bf16 bf16x8 __attribute__((ext_vector_type(8)));

__device__ __forceinline__ uint32_t cvt_pk_bf16(float lo, float hi) {
  uint32_t d;
  asm("v_cvt_pk_bf16_f32 %0, %1, %2" : "=v"(d) : "v"(lo), "v"(hi));
  return d;
}

// max over all 64 lanes; result valid in lane 63
__device__ __forceinline__ float dpp_max64(float v) {
  float r = v; int x;
  x = __builtin_amdgcn_update_dpp(__float_as_int(r), __float_as_int(r), 0x111, 0xF, 0xF, false); r = fmaxf(r, __int_as_float(x));
  x = __builtin_amdgcn_update_dpp(__float_as_int(r), __float_as_int(r), 0x112, 0xF, 0xF, false); r = fmaxf(r, __int_as_float(x));
  x = __builtin_amdgcn_update_dpp(__float_as_int(r), __float_as_int(r), 0x114, 0xF, 0xF, false); r = fmaxf(r, __int_as_float(x));
  x = __builtin_amdgcn_update_dpp(__float_as_int(r), __float_as_int(r), 0x118, 0xF, 0xF, false); r = fmaxf(r, __int_as_float(x));
  x = __builtin_amdgcn_update_dpp(__float_as_int(r), __float_as_int(r), 0x142, 0xF, 0xF, false); r = fmaxf(r, __int_as_float(x));
  x = __builtin_amdgcn_update_dpp(__float_as_int(r), __float_as_int(r), 0x143, 0xF, 0xF, false); r = fmaxf(r, __int_as_float(x));
  return r;
}

// slot bijection shared by: MFMA C-row layout (HW-verified), scan A^T-frag,
// scan B-frag, blin state pairing, pivec reset.
//   state(h, r) = (r&3) + 8*((r>>2)&1) + 4*h + 16*(r>>3),  r in [0,16)

// ---------------- K1: preprocess
__global__ __launch_bounds__(1024) void k_pre(
    const float* __restrict__ tm, const float* __restrict__ sp,
    const float* __restrict__ mus, const float* __restrict__ lv,
    float* __restrict__ pivec, uint32_t* __restrict__ Wp,
    float* __restrict__ bias, uint32_t* __restrict__ Af)
{
  __shared__ float As[32][32];
  const int tid = threadIdx.x;       // 0..1023
  const int row = tid >> 5;          // 0..31
  const int col = tid & 31;          // 0..31

  // --- transition-matrix row softmax -> LDS
  {
    float v = tm[row * 32 + col];
    float m = v;
    #pragma unroll
    for (int mask = 16; mask; mask >>= 1) m = fmaxf(m, __shfl_xor(m, mask));
    float e = __expf(v - m);
    float s = e;
    #pragma unroll
    for (int mask = 16; mask; mask >>= 1) s += __shfl_xor(s, mask);
    As[row][col] = e / s;
  }

  // --- state-prior softmax (lanes 0..31 of wave 0)
  if (tid < 32) {
    float v = sp[tid];
    float m = v;
    #pragma unroll
    for (int mask = 16; mask; mask >>= 1) m = fmaxf(m, __shfl_xor(m, mask));
    float e = __expf(v - m);
    float s = e;
    #pragma unroll
    for (int mask = 16; mask; mask >>= 1) s += __shfl_xor(s, mask);
    pivec[tid] = e / s;
  }

  // --- Wp fragment table for k_emis (bf16 pairs)
  #pragma unroll
  for (int hh = 0; hh < 2; ++hh) {
    int d = col + (hh << 5);             // 0..63
    float iv = __expf(-lv[row * 64 + d]);
    uint32_t w = cvt_pk_bf16(-0.5f * iv, mus[row * 64 + d] * iv);
    int kk = d >> 3, h2 = (d >> 2) & 1, j = d & 3;
    Wp[(((row << 1) + h2) * 8 + kk) * 4 + j] = w;
  }

  // --- bias[n]
  {
    float s2 = 0.f, slv = 0.f;
    #pragma unroll
    for (int h = 0; h < 2; ++h) {
      int d = col + h * 32;
      float m_ = mus[row * 64 + d];
      float l_ = lv[row * 64 + d];
      s2 = fmaf(m_ * m_, __expf(-l_), s2);
      slv += l_;
    }
    #pragma unroll
    for (int mask = 16; mask; mask >>= 1) {
      s2  += __shfl_xor(s2, mask);
      slv += __shfl_xor(slv, mask);
    }
    if (col == 0) bias[row] = -0.5f * (s2 + slv + (float)DD * LOG2PI);
  }

  __syncthreads();

  // --- A^T fragment table (scan MFMA A-operand)
  if (tid < 512) {
    int l = tid >> 3, s = tid & 7;
    int m = s >> 2, p = s & 3;
    int j = l & 31, hh = l >> 5;
    int r0 = 2 * p, r1 = r0 + 1;
    int s0 = (r0 & 3) + 8 * ((r0 >> 2) & 1) + 4 * hh + 16 * m;
    int s1 = (r1 & 3) + 8 * ((r1 >> 2) & 1) + 4 * hh + 16 * m;
    Af[(l << 3) + (m << 2) + p] = cvt_pk_bf16(As[s0][j], As[s1][j]);
  }
}

// ---------------- K2: emission via MFMA -> blin (bf16, per-16-t-chunk max)
// R13: X staged through LDS (R12 fix: stage ALL 2048 granules, ii<8).
// Global reads perfectly coalesced (thread tid -> contiguous uint4);
// granule-XOR swizzle (q ^= row&15) on BOTH LDS write and transpose read
// -> 4 lanes/bank-quad (b128 floor). Low-VGPR inner loop.
__global__ __launch_bounds__(256, 4) void k_emis(
    const float* __restrict__ Xg,
    const uint32_t* __restrict__ Wp,
    const float* __restrict__ bias,
    uint32_t* __restrict__ blin32,
    float* __restrict__ Kc)
{
  __shared__ uint4 Xs[2048];           // 32 KB: 128 rows x 16 granules (swizzled)
  const int tid = threadIdx.x;
  const int l   = tid & 63;
  const int w   = tid >> 6;            // wave 0..3
  const int bid = blockIdx.x;          // 0..2047
  const int b   = bid >> 5;
  const int slab = bid & 31;           // 128-row slab within subject
  const int t0s = slab << 7;

  // --- stage X slab (coalesced) with granule swizzle: 2048 granules, 8 iters
  {
    const uint4* xg = (const uint4*)(Xg + (size_t)(b * TT + t0s) * DD);
    #pragma unroll
    for (int ii = 0; ii < 8; ++ii) {
      int G = (ii << 8) + tid;         // flat granule 0..2047: row=G>>4, q=G&15
      uint4 vv = xg[G];
      int row = G >> 4, q = G & 15;
      Xs[(row << 4) + (q ^ (row & 15))] = vv;
    }
  }
  __syncthreads();

  const int chunk = (slab << 2) + w;   // 32-t window 0..127
  const int t0w = chunk << 5;
  const int n   = l & 31;
  const int h   = l >> 5;
  const int rloc = (w << 5) + n;       // slab-local row this lane transposes

  uint4 wf[8];
  const uint4* wp4 = (const uint4*)(Wp + ((n << 1) + h) * 32);
  #pragma unroll
  for (int kk = 0; kk < 8; ++kk) wf[kk] = wp4[kk];

  f32x16 acc;
  #pragma unroll
  for (int r = 0; r < 16; ++r) acc[r] = 0.0f;

  #pragma unroll
  for (int kk = 0; kk < 8; ++kk) {
    uint4 xu = Xs[(rloc << 4) + (((kk << 1) | h) ^ (rloc & 15))];
    float4 x4 = __builtin_bit_cast(float4, xu);
    uint4 au;
    au.x = cvt_pk_bf16(x4.x * x4.x, x4.x);
    au.y = cvt_pk_bf16(x4.y * x4.y, x4.y);
    au.z = cvt_pk_bf16(x4.z * x4.z, x4.z);
    au.w = cvt_pk_bf16(x4.w * x4.w, x4.w);
    bf16x8 af = __builtin_bit_cast(bf16x8, au);
    bf16x8 bf = __builtin_bit_cast(bf16x8, wf[kk]);
    acc = __builtin_amdgcn_mfma_f32_32x32x16_bf16(af, bf, acc, 0, 0, 0);
  }

  const float bn = bias[n];
  float lb[16];
  float m0 = -1e30f, m1 = -1e30f;
  #pragma unroll
  for (int r = 0; r < 16; ++r) {
    lb[r] = acc[r] + bn;
    if (r < 8) m0 = fmaxf(m0, lb[r]); else m1 = fmaxf(m1, lb[r]);
  }
  m0 = dpp_max64(m0);
  m1 = dpp_max64(m1);
  const float Km0 = __int_as_float(__builtin_amdgcn_readlane(__float_as_int(m0), 63));
  const float Km1 = __int_as_float(__builtin_amdgcn_readlane(__float_as_int(m1), 63));
  if (l == 0) {
    Kc[(b << 8) + (chunk << 1)]     = Km0;
    Kc[(b << 8) + (chunk << 1) + 1] = Km1;
  }

  const int tb = b * TT + t0w;
  #pragma unroll
  for (int r = 0; r < 16; ++r) {
    float e = __expf(lb[r] - ((r < 8) ? Km0 : Km1));
    int nb = __builtin_amdgcn_update_dpp(0, __float_as_int(e), 0xB1, 0xF, 0xF, true); // lane^1
    uint32_t pk = cvt_pk_bf16(e, __int_as_float(nb));   // lo = even n, hi = odd n
    const int trow = (r & 3) + ((r >> 2) << 3) + (h << 2);
    if ((l & 1) == 0)
      blin32[(size_t)(tb + trow) * 16 + (n >> 1)] = pk;
  }
}

// ---------------- K3: MFMA-batched linear-space scan
// One wave = 32 chunks (lane col = chunk; 16 C-regs = that chunk's states).
// Step: V' = (A^T (rf*V)) . b_t. Slot bijection == C-row layout -> MFMA
// output regs feed the next B-frag directly (no cross-lane movement).
__global__ __launch_bounds__(256) void k_scan(
    const uint32_t* __restrict__ blin32,
    const float* __restrict__ Kc,
    const uint32_t* __restrict__ Af,
    const float* __restrict__ pivec,
    float* __restrict__ out,
    float* __restrict__ Mc)
{
  const int tid = threadIdx.x;
  const int l   = tid & 63;
  const int w   = tid >> 6;
  const int g   = (blockIdx.x << 2) + w;   // 0..511
  const int b   = g >> 3;
  const int cb  = g & 7;
  const int col = l & 31;
  const int h   = l >> 5;
  const int c   = (cb << 5) + col;         // chunk 0..255
  const bool isC0 = (c == 0);

  const uint4 af0u = *(const uint4*)(Af + (l << 3));
  const uint4 af1u = *(const uint4*)(Af + (l << 3) + 4);
  const bf16x8 af0 = __builtin_bit_cast(bf16x8, af0u);
  const bf16x8 af1 = __builtin_bit_cast(bf16x8, af1u);

  const float KcH = Kc[(b << 8) + c];
  const int outbase = b * TT + (c << 4);
  const int base0 = (b * TT + (c << 4) - WU) * 16 + (h << 1);
  const int baseClamp = b * TT * 16 + (h << 1);

  uint32_t blA[8], blB[8];
  #define LOADB(Q, B) { \
    int i0 = base0 + (Q) * 16; if (i0 < baseClamp) i0 = baseClamp; \
    const uint32_t* p = blin32 + i0; \
    uint2 u0 = *(const uint2*)(p); \
    uint2 u1 = *(const uint2*)(p + 4); \
    uint2 u2 = *(const uint2*)(p + 8); \
    uint2 u3 = *(const uint2*)(p + 12); \
    B[0]=u0.x; B[1]=u0.y; B[2]=u1.x; B[3]=u1.y; \
    B[4]=u2.x; B[5]=u2.y; B[6]=u3.x; B[7]=u3.y; }
  LOADB(0, blA)
  LOADB(1, blB)

  f32x16 zv;
  #pragma unroll
  for (int r = 0; r < 16; ++r) zv[r] = 0.0f;

  float v[16];
  #pragma unroll
  for (int r = 0; r < 16; ++r) v[r] = 1.0f;
  float S = 0.0f, sPrev = 1.0f;

  #define SCAN_STEP(Q, CUR) { \
    float sP = fmaxf(sPrev, FLT_MIN_NORM); \
    int e = ((__float_as_int(sP) >> 23) & 0xFF) - 126; \
    float rf = __int_as_float((127 - e) << 23); \
    if ((Q) >= WU) { \
      float outv = __log2f(sP) * LN2F + S; \
      if ((Q) == WU) { if (h == 0) Mc[(b << 8) + c] = outv; } \
      else           { if (h == 0) out[outbase + (Q) - WU - 1] = outv; } \
      S += KcH + (float)e * LN2F; \
    } else { S += (float)e * LN2F; } \
    float vr[16]; \
    _Pragma("unroll") \
    for (int r = 0; r < 16; ++r) vr[r] = v[r] * rf; \
    uint32_t p2[8]; \
    _Pragma("unroll") \
    for (int i = 0; i < 8; ++i) p2[i] = cvt_pk_bf16(vr[2*i], vr[2*i+1]); \
    uint4 b0u; b0u.x = p2[0]; b0u.y = p2[1]; b0u.z = p2[2]; b0u.w = p2[3]; \
    uint4 b1u; b1u.x = p2[4]; b1u.y = p2[5]; b1u.z = p2[6]; b1u.w = p2[7]; \
    f32x16 acc = __builtin_amdgcn_mfma_f32_32x32x16_bf16(af0, __builtin_bit_cast(bf16x8, b0u), zv, 0, 0, 0); \
    acc = __builtin_amdgcn_mfma_f32_32x32x16_bf16(af1, __builtin_bit_cast(bf16x8, b1u), acc, 0, 0, 0); \
    _Pragma("unroll") \
    for (int i = 0; i < 8; ++i) { \
      float blo = __int_as_float(CUR[i] << 16); \
      float bhi = __int_as_float(CUR[i] & 0xFFFF0000u); \
      float d0 = acc[2*i], d1 = acc[2*i+1]; \
      if ((Q) == WU) { if (isC0) { d0 = vr[2*i]; d1 = vr[2*i+1]; } } \
      v[2*i]   = d0 * blo; \
      v[2*i+1] = d1 * bhi; \
    } \
    if ((Q) == WU - 1) { \
      if (isC0) { \
        _Pragma("unroll") \
        for (int r = 0; r < 16; ++r) \
          v[r] = pivec[(r & 3) + 8 * ((r >> 2) & 1) + (h << 2) + ((r >> 3) << 4)]; \
        S = 0.0f; \
      } \
    } \
    float s8[8]; \
    _Pragma("unroll") \
    for (int i = 0; i < 8; ++i) s8[i] = v[2*i] + v[2*i+1]; \
    float s4a = s8[0] + s8[1], s4b = s8[2] + s8[3]; \
    float s4c = s8[4] + s8[5], s4d = s8[6] + s8[7]; \
    float s = (s4a + s4b) + (s4c + s4d); \
    s += __shfl_xor(s, 32); \
    sPrev = s; \
    if ((Q) + 2 < NSTEPS) LOADB((Q) + 2, CUR) \
  }

  #pragma unroll
  for (int m = 0; m < NSTEPS / 2; ++m) {
    SCAN_STEP(2 * m,     blA)
    SCAN_STEP(2 * m + 1, blB)
  }
  #undef SCAN_STEP
  #undef LOADB

  {
    float sP = fmaxf(sPrev, FLT_MIN_NORM);
    if (h == 0) out[outbase + CL - 1] = __log2f(sP) * LN2F + S;
  }
}

// ---------------- K4a: per-subject prefix of chunk offsets (256 chunks)
__global__ void k_stitch(const float* __restrict__ out, const float* __restrict__ Mcc,
                         float* __restrict__ Delta)
{
  __shared__ float wsum[4];
  const int b  = blockIdx.x;
  const int c  = threadIdx.x;     // 0..255 (4 waves)
  const int wv = c >> 6, ln = c & 63;
  float term = 0.0f;
  if (c > 0) term = out[b * TT + (c << 4) - 1] - Mcc[(b << 8) + c];
  for (int off = 1; off < 64; off <<= 1) {
    float up = __shfl_up(term, off);
    if (ln >= off) term += up;
  }
  if (ln == 63) wsum[wv] = term;
  __syncthreads();
  float add = 0.0f;
  for (int i = 0; i < wv; ++i) add += wsum[i];
  Delta[(b << 8) + c] = term + add;
}

// ---------------- K4b: add offsets
__global__ void k_add(float* __restrict__ out, const float* __restrict__ Delta)
{
  const int i = blockIdx.x * 256 + threadIdx.x;   // i < B*T
  const int b = i >> 12;
  const int t = i & 4095;
  out[i] += Delta[(b << 8) + (t >> 4)];
}

extern "C" void kernel_launch(void* const* d_in, const int* in_sizes, int n_in,
                              void* d_out, int out_size, void* d_ws, size_t ws_size,
                              hipStream_t stream) {
  const float* X   = (const float*)d_in[0];
  const float* tm  = (const float*)d_in[1];
  const float* sp  = (const float*)d_in[2];
  const float* mus = (const float*)d_in[3];
  const float* lv  = (const float*)d_in[4];
  float* out = (float*)d_out;

  char* ws = (char*)d_ws;
  size_t off = 0;
  uint32_t* blin32 = (uint32_t*)(ws + off); off += (size_t)BB * TT * NS * 2 + 4096;
  float* Kcv   = (float*)(ws + off); off += (size_t)BB * CH * 4;
  float* Mcc   = (float*)(ws + off); off += (size_t)BB * CH * 4;
  float* Delta = (float*)(ws + off); off += (size_t)BB * CH * 4;
  float* pivec = (float*)(ws + off); off += 256;
  uint32_t* Wp = (uint32_t*)(ws + off); off += (size_t)2048 * 4;
  float* bias  = (float*)(ws + off); off += 256;
  uint32_t* Af = (uint32_t*)(ws + off); off += (size_t)512 * 4;

  k_pre<<<dim3(1), dim3(1024), 0, stream>>>(tm, sp, mus, lv, pivec, Wp, bias, Af);
  k_emis<<<dim3(2048), dim3(256), 0, stream>>>(X, Wp, bias, blin32, Kcv);
  k_scan<<<dim3(128), dim3(256), 0, stream>>>(blin32, Kcv, Af, pivec, out, Mcc);
  k_stitch<<<dim3(BB), dim3(256), 0, stream>>>(out, Mcc, Delta);
  k_add<<<dim3((BB * TT) / 256), dim3(256), 0, stream>>>(out, Delta);
}

// Round 14
// 34.070 us; speedup vs baseline: 2.2673x; 1.3610x over previous
//
#include <hip/hip_runtime.h>
#include <hip/hip_bf16.h>
#include <stdint.h>

#define BB 64
#define TT 4096
#define NS 32
#define DD 64
#define CH 256     // chunks per subject
#define CL 16      // chunk length
#define WU 8       // warmup steps (Birkhoff tau~0.15/step -> ~3e-7 after 8)
#define NSTEPS (WU + CL)
#define LOG2PI 1.8378770664093453f
#define LN2F 0.6931471805599453f
#define FLT_MIN_NORM 1.175494350822288e-38f

typedef float f32x16 __attribute__((ext_vector_type(16)));
typedef __bf16 bf16x8 __attribute__((ext_vector_type(8)));

__device__ __forceinline__ uint32_t cvt_pk_bf16(float lo, float hi) {
  uint32_t d;
  asm("v_cvt_pk_bf16_f32 %0, %1, %2" : "=v"(d) : "v"(lo), "v"(hi));
  return d;
}

// max over all 64 lanes; result valid in lane 63
__device__ __forceinline__ float dpp_max64(float v) {
  float r = v; int x;
  x = __builtin_amdgcn_update_dpp(__float_as_int(r), __float_as_int(r), 0x111, 0xF, 0xF, false); r = fmaxf(r, __int_as_float(x));
  x = __builtin_amdgcn_update_dpp(__float_as_int(r), __float_as_int(r), 0x112, 0xF, 0xF, false); r = fmaxf(r, __int_as_float(x));
  x = __builtin_amdgcn_update_dpp(__float_as_int(r), __float_as_int(r), 0x114, 0xF, 0xF, false); r = fmaxf(r, __int_as_float(x));
  x = __builtin_amdgcn_update_dpp(__float_as_int(r), __float_as_int(r), 0x118, 0xF, 0xF, false); r = fmaxf(r, __int_as_float(x));
  x = __builtin_amdgcn_update_dpp(__float_as_int(r), __float_as_int(r), 0x142, 0xF, 0xF, false); r = fmaxf(r, __int_as_float(x));
  x = __builtin_amdgcn_update_dpp(__float_as_int(r), __float_as_int(r), 0x143, 0xF, 0xF, false); r = fmaxf(r, __int_as_float(x));
  return r;
}

// slot bijection shared by: MFMA C-row layout (HW-verified), scan A^T-frag,
// scan B-frag, blin state pairing, pivec reset.
//   state(h, r) = (r&3) + 8*((r>>2)&1) + 4*h + 16*(r>>3),  r in [0,16)

// ---------------- K1: preprocess (unchanged from R13)
__global__ __launch_bounds__(1024) void k_pre(
    const float* __restrict__ tm, const float* __restrict__ sp,
    const float* __restrict__ mus, const float* __restrict__ lv,
    float* __restrict__ pivec, uint32_t* __restrict__ Wp,
    float* __restrict__ bias, uint32_t* __restrict__ Af)
{
  __shared__ float As[32][32];
  const int tid = threadIdx.x;       // 0..1023
  const int row = tid >> 5;          // 0..31
  const int col = tid & 31;          // 0..31

  {
    float v = tm[row * 32 + col];
    float m = v;
    #pragma unroll
    for (int mask = 16; mask; mask >>= 1) m = fmaxf(m, __shfl_xor(m, mask));
    float e = __expf(v - m);
    float s = e;
    #pragma unroll
    for (int mask = 16; mask; mask >>= 1) s += __shfl_xor(s, mask);
    As[row][col] = e / s;
  }

  if (tid < 32) {
    float v = sp[tid];
    float m = v;
    #pragma unroll
    for (int mask = 16; mask; mask >>= 1) m = fmaxf(m, __shfl_xor(m, mask));
    float e = __expf(v - m);
    float s = e;
    #pragma unroll
    for (int mask = 16; mask; mask >>= 1) s += __shfl_xor(s, mask);
    pivec[tid] = e / s;
  }

  #pragma unroll
  for (int hh = 0; hh < 2; ++hh) {
    int d = col + (hh << 5);             // 0..63
    float iv = __expf(-lv[row * 64 + d]);
    uint32_t w = cvt_pk_bf16(-0.5f * iv, mus[row * 64 + d] * iv);
    int kk = d >> 3, h2 = (d >> 2) & 1, j = d & 3;
    Wp[(((row << 1) + h2) * 8 + kk) * 4 + j] = w;
  }

  {
    float s2 = 0.f, slv = 0.f;
    #pragma unroll
    for (int h = 0; h < 2; ++h) {
      int d = col + h * 32;
      float m_ = mus[row * 64 + d];
      float l_ = lv[row * 64 + d];
      s2 = fmaf(m_ * m_, __expf(-l_), s2);
      slv += l_;
    }
    #pragma unroll
    for (int mask = 16; mask; mask >>= 1) {
      s2  += __shfl_xor(s2, mask);
      slv += __shfl_xor(slv, mask);
    }
    if (col == 0) bias[row] = -0.5f * (s2 + slv + (float)DD * LOG2PI);
  }

  __syncthreads();

  if (tid < 512) {
    int l = tid >> 3, s = tid & 7;
    int m = s >> 2, p = s & 3;
    int j = l & 31, hh = l >> 5;
    int r0 = 2 * p, r1 = r0 + 1;
    int s0 = (r0 & 3) + 8 * ((r0 >> 2) & 1) + 4 * hh + 16 * m;
    int s1 = (r1 & 3) + 8 * ((r1 >> 2) & 1) + 4 * hh + 16 * m;
    Af[(l << 3) + (m << 2) + p] = cvt_pk_bf16(As[s0][j], As[s1][j]);
  }
}

// ---------------- K2: FUSED emission + scan
// Block = (subject b, 512-row superblock cb) = 32 chunks of 16.
// Emis phase: 4 waves x 17 windows (16 real + warmup overlap) -> blin in LDS
// (544 rows x 64 B, slot-XOR swizzle ((row>>4)&7)<<1: write 2-way free,
// scan read <=4-way). Scan phase: wave 0 runs the 32-chunk MFMA scan from LDS.
// blin NEVER touches HBM.
__global__ __launch_bounds__(256) void k_fused(
    const float* __restrict__ Xg,
    const uint32_t* __restrict__ Wp,
    const float* __restrict__ bias,
    const uint32_t* __restrict__ Af,
    const float* __restrict__ pivec,
    float* __restrict__ out,
    float* __restrict__ Mc)
{
  __shared__ uint32_t blinL[544 * 16];   // 34 KB
  __shared__ float KcL[32];
  const int tid = threadIdx.x;
  const int l   = tid & 63;
  const int wv  = tid >> 6;            // wave 0..3
  const int g   = blockIdx.x;          // 0..511
  const int b   = g >> 3;
  const int cb  = g & 7;
  const int t0  = cb << 9;             // superblock start t
  const int n   = l & 31;
  const int h   = l >> 5;

  // hoisted emis B-frags + bias
  uint4 wf[8];
  const uint4* wp4 = (const uint4*)(Wp + ((n << 1) + h) * 32);
  #pragma unroll
  for (int kk = 0; kk < 8; ++kk) wf[kk] = wp4[kk];
  const float bn = bias[n];

  // ---- emis phase: windows wi=0 (warmup overlap) .. 16
  for (int wi = wv; wi < 17; wi += 4) {
    if (cb == 0 && wi == 0) continue;            // chunk-0 clamp handles it
    const int wbase = t0 - 32 + (wi << 5);       // global t of window row 0
    const float* xr = Xg + (size_t)(b * TT + wbase + n) * DD + (h << 2);

    f32x16 acc;
    #pragma unroll
    for (int r = 0; r < 16; ++r) acc[r] = 0.0f;

    #pragma unroll
    for (int kk = 0; kk < 8; ++kk) {
      float4 x4 = *(const float4*)(xr + (kk << 3));
      uint4 au;
      au.x = cvt_pk_bf16(x4.x * x4.x, x4.x);
      au.y = cvt_pk_bf16(x4.y * x4.y, x4.y);
      au.z = cvt_pk_bf16(x4.z * x4.z, x4.z);
      au.w = cvt_pk_bf16(x4.w * x4.w, x4.w);
      bf16x8 af = __builtin_bit_cast(bf16x8, au);
      bf16x8 bf = __builtin_bit_cast(bf16x8, wf[kk]);
      acc = __builtin_amdgcn_mfma_f32_32x32x16_bf16(af, bf, acc, 0, 0, 0);
    }

    float lb[16];
    float m0 = -1e30f, m1 = -1e30f;
    #pragma unroll
    for (int r = 0; r < 16; ++r) {
      lb[r] = acc[r] + bn;
      if (r < 8) m0 = fmaxf(m0, lb[r]); else m1 = fmaxf(m1, lb[r]);
    }
    m0 = dpp_max64(m0);
    m1 = dpp_max64(m1);
    const float Km0 = __int_as_float(__builtin_amdgcn_readlane(__float_as_int(m0), 63));
    const float Km1 = __int_as_float(__builtin_amdgcn_readlane(__float_as_int(m1), 63));
    if (wi >= 1 && l == 0) {
      KcL[((wi - 1) << 1)]     = Km0;
      KcL[((wi - 1) << 1) + 1] = Km1;
    }

    const int rb = wi << 5;                      // LDS row of window row 0
    #pragma unroll
    for (int r = 0; r < 16; ++r) {
      float e = __expf(lb[r] - ((r < 8) ? Km0 : Km1));
      int nb = __builtin_amdgcn_update_dpp(0, __float_as_int(e), 0xB1, 0xF, 0xF, true); // lane^1
      uint32_t pk = cvt_pk_bf16(e, __int_as_float(nb));   // lo = even n, hi = odd n
      const int ldsrow = rb + (r & 3) + ((r >> 2) << 3) + (h << 2);
      if ((l & 1) == 0)
        blinL[ldsrow * 16 + ((n >> 1) ^ (((ldsrow >> 4) & 7) << 1))] = pk;
    }
  }
  __syncthreads();
  if (wv != 0) return;

  // ---- scan phase (wave 0 only): 32 chunks, lane col = chunk
  const int col = n;
  const int c   = (cb << 5) + col;               // chunk 0..255
  const bool isC0 = (cb == 0) && (col == 0);

  const uint4 af0u = *(const uint4*)(Af + (l << 3));
  const uint4 af1u = *(const uint4*)(Af + (l << 3) + 4);
  const bf16x8 af0 = __builtin_bit_cast(bf16x8, af0u);
  const bf16x8 af1 = __builtin_bit_cast(bf16x8, af1u);

  const float KcH = KcL[col];
  const int outbase = b * TT + (c << 4);

  f32x16 zv;
  #pragma unroll
  for (int r = 0; r < 16; ++r) zv[r] = 0.0f;

  float v[16];
  #pragma unroll
  for (int r = 0; r < 16; ++r) v[r] = 1.0f;
  float S = 0.0f, sPrev = 1.0f;

  #pragma unroll
  for (int q = 0; q < NSTEPS; ++q) {
    float sP = fmaxf(sPrev, FLT_MIN_NORM);
    int e = ((__float_as_int(sP) >> 23) & 0xFF) - 126;
    float rf = __int_as_float((127 - e) << 23);
    if (q >= WU) {
      float outv = __log2f(sP) * LN2F + S;
      if (q == WU) { if (h == 0) Mc[(b << 8) + c] = outv; }
      else         { if (h == 0) out[outbase + q - WU - 1] = outv; }
      S += KcH + (float)e * LN2F;
    } else {
      S += (float)e * LN2F;
    }

    // read b_t row from LDS (logical slots {h2,h2+1, +4, +8, +12})
    int ldsrow = 24 + (col << 4) + q;
    if (cb == 0 && ldsrow < 32) ldsrow = 32;     // chunk-0 clamp
    const int swz = ((ldsrow >> 4) & 7) << 1;
    const uint32_t* p = blinL + ldsrow * 16;
    const int h2 = h << 1;
    uint2 u0 = *(const uint2*)(p + (h2 ^ swz));
    uint2 u1 = *(const uint2*)(p + ((h2 + 4) ^ swz));
    uint2 u2 = *(const uint2*)(p + ((h2 + 8) ^ swz));
    uint2 u3 = *(const uint2*)(p + ((h2 + 12) ^ swz));
    uint32_t CUR[8];
    CUR[0] = u0.x; CUR[1] = u0.y; CUR[2] = u1.x; CUR[3] = u1.y;
    CUR[4] = u2.x; CUR[5] = u2.y; CUR[6] = u3.x; CUR[7] = u3.y;

    float vr[16];
    #pragma unroll
    for (int r = 0; r < 16; ++r) vr[r] = v[r] * rf;
    uint32_t p2[8];
    #pragma unroll
    for (int i = 0; i < 8; ++i) p2[i] = cvt_pk_bf16(vr[2*i], vr[2*i+1]);
    uint4 b0u; b0u.x = p2[0]; b0u.y = p2[1]; b0u.z = p2[2]; b0u.w = p2[3];
    uint4 b1u; b1u.x = p2[4]; b1u.y = p2[5]; b1u.z = p2[6]; b1u.w = p2[7];
    f32x16 acc = __builtin_amdgcn_mfma_f32_32x32x16_bf16(af0, __builtin_bit_cast(bf16x8, b0u), zv, 0, 0, 0);
    acc = __builtin_amdgcn_mfma_f32_32x32x16_bf16(af1, __builtin_bit_cast(bf16x8, b1u), acc, 0, 0, 0);

    #pragma unroll
    for (int i = 0; i < 8; ++i) {
      float blo = __int_as_float(CUR[i] << 16);
      float bhi = __int_as_float(CUR[i] & 0xFFFF0000u);
      float d0 = acc[2*i], d1 = acc[2*i+1];
      if (q == WU) { if (isC0) { d0 = vr[2*i]; d1 = vr[2*i+1]; } }
      v[2*i]   = d0 * blo;
      v[2*i+1] = d1 * bhi;
    }
    if (q == WU - 1) {
      if (isC0) {
        #pragma unroll
        for (int r = 0; r < 16; ++r)
          v[r] = pivec[(r & 3) + 8 * ((r >> 2) & 1) + (h << 2) + ((r >> 3) << 4)];
        S = 0.0f;
      }
    }
    float s8[8];
    #pragma unroll
    for (int i = 0; i < 8; ++i) s8[i] = v[2*i] + v[2*i+1];
    float s4a = s8[0] + s8[1], s4b = s8[2] + s8[3];
    float s4c = s8[4] + s8[5], s4d = s8[6] + s8[7];
    float s = (s4a + s4b) + (s4c + s4d);
    s += __shfl_xor(s, 32);
    sPrev = s;
  }

  {
    float sP = fmaxf(sPrev, FLT_MIN_NORM);
    if (h == 0) out[outbase + CL - 1] = __log2f(sP) * LN2F + S;
  }
}

// ---------------- K4a: per-subject prefix of chunk offsets (256 chunks)
__global__ void k_stitch(const float* __restrict__ out, const float* __restrict__ Mcc,
                         float* __restrict__ Delta)
{
  __shared__ float wsum[4];
  const int b  = blockIdx.x;
  const int c  = threadIdx.x;     // 0..255 (4 waves)
  const int wv = c >> 6, ln = c & 63;
  float term = 0.0f;
  if (c > 0) term = out[b * TT + (c << 4) - 1] - Mcc[(b << 8) + c];
  for (int off = 1; off < 64; off <<= 1) {
    float up = __shfl_up(term, off);
    if (ln >= off) term += up;
  }
  if (ln == 63) wsum[wv] = term;
  __syncthreads();
  float add = 0.0f;
  for (int i = 0; i < wv; ++i) add += wsum[i];
  Delta[(b << 8) + c] = term + add;
}

// ---------------- K4b: add offsets
__global__ void k_add(float* __restrict__ out, const float* __restrict__ Delta)
{
  const int i = blockIdx.x * 256 + threadIdx.x;   // i < B*T
  const int b = i >> 12;
  const int t = i & 4095;
  out[i] += Delta[(b << 8) + (t >> 4)];
}

extern "C" void kernel_launch(void* const* d_in, const int* in_sizes, int n_in,
                              void* d_out, int out_size, void* d_ws, size_t ws_size,
                              hipStream_t stream) {
  const float* X   = (const float*)d_in[0];
  const float* tm  = (const float*)d_in[1];
  const float* sp  = (const float*)d_in[2];
  const float* mus = (const float*)d_in[3];
  const float* lv  = (const float*)d_in[4];
  float* out = (float*)d_out;

  char* ws = (char*)d_ws;
  size_t off = 0;
  float* Mcc   = (float*)(ws + off); off += (size_t)BB * CH * 4;
  float* Delta = (float*)(ws + off); off += (size_t)BB * CH * 4;
  float* pivec = (float*)(ws + off); off += 256;
  uint32_t* Wp = (uint32_t*)(ws + off); off += (size_t)2048 * 4;
  float* bias  = (float*)(ws + off); off += 256;
  uint32_t* Af = (uint32_t*)(ws + off); off += (size_t)512 * 4;

  k_pre<<<dim3(1), dim3(1024), 0, stream>>>(tm, sp, mus, lv, pivec, Wp, bias, Af);
  k_fused<<<dim3(512), dim3(256), 0, stream>>>(X, Wp, bias, Af, pivec, out, Mcc);
  k_stitch<<<dim3(BB), dim3(256), 0, stream>>>(out, Mcc, Delta);
  k_add<<<dim3((BB * TT) / 256), dim3(256), 0, stream>>>(out, Delta);
}